// Round 1
// baseline (398.129 us; speedup 1.0000x reference)
//
#include <hip/hip_runtime.h>

typedef short s16x8 __attribute__((ext_vector_type(8)));
typedef float f32x4 __attribute__((ext_vector_type(4)));
typedef unsigned short u16x4 __attribute__((ext_vector_type(4)));

#define DEV static __device__ __forceinline__

DEV unsigned short f2bf(float f) {
  union { float f; unsigned u; } v; v.f = f;
  unsigned r = v.u + 0x7FFFu + ((v.u >> 16) & 1u);
  return (unsigned short)(r >> 16);
}

#define GLDS16(src, dst) \
  __builtin_amdgcn_global_load_lds((const __attribute__((address_space(1))) void*)(src), \
                                   (__attribute__((address_space(3))) void*)(dst), 16, 0, 0)

#define MFMA(a, b, c) __builtin_amdgcn_mfma_f32_16x16x32_bf16((a), (b), (c), 0, 0, 0)

// ---------------- elementwise fp32 -> bf16 ----------------
__global__ __launch_bounds__(256) void k_f32_to_bf16(const float* __restrict__ in,
                                                     unsigned short* __restrict__ out, int n4) {
  int i = blockIdx.x * 256 + threadIdx.x;
  if (i >= n4) return;
  float4 v = ((const float4*)in)[i];
  u16x4 o; o.x = f2bf(v.x); o.y = f2bf(v.y); o.z = f2bf(v.z); o.w = f2bf(v.w);
  ((u16x4*)out)[i] = o;
}

// ---------------- weight transpose+convert: (K,N) f32 -> (N,K) bf16 ----------------
__global__ __launch_bounds__(256) void k_transpose_w(const float* __restrict__ W,
                                                     unsigned short* __restrict__ Wt,
                                                     int K, int N) {
  __shared__ float t[64][65];
  int k0 = blockIdx.x * 64, n0 = blockIdx.y * 64;
  int tid = threadIdx.x;
#pragma unroll
  for (int i = 0; i < 16; ++i) {
    int idx = tid + i * 256; int r = idx >> 6, c = idx & 63;
    t[r][c] = W[(size_t)(k0 + r) * N + (n0 + c)];
  }
  __syncthreads();
#pragma unroll
  for (int i = 0; i < 16; ++i) {
    int idx = tid + i * 256; int r = idx >> 6, c = idx & 63;
    Wt[(size_t)(n0 + r) * K + (k0 + c)] = f2bf(t[c][r]);
  }
}

// ---------------- concat 3 bias vectors ----------------
__global__ void k_concat3(const float* __restrict__ a, const float* __restrict__ b,
                          const float* __restrict__ c, float* __restrict__ out, int n) {
  int i = blockIdx.x * 256 + threadIdx.x;
  if (i >= 3 * n) return;
  int j = (i < n) ? i : (i < 2 * n ? i - n : i - 2 * n);
  out[i] = (i < n) ? a[j] : (i < 2 * n ? b[j] : c[j]);
}

// ---------------- GEMM: C = A(MxK) * Bt(NxK)^T + bias ----------------
// MODE 0: bf16 out. MODE 1: bf16 out + relu. MODE 2: f32 out + residual + LN partials.
template <int MODE>
__global__ __launch_bounds__(256) void k_gemm(
    const unsigned short* __restrict__ A, int lda,
    const unsigned short* __restrict__ Bt, int ldb,
    const float* __restrict__ bias,
    unsigned short* __restrict__ Cb, float* __restrict__ Cf, int ldc,
    const float* __restrict__ resid, float* __restrict__ partials,
    int K, int rows_per_batch, int n_tiles_n) {
  __shared__ __align__(16) unsigned short As[128 * 64];
  __shared__ __align__(16) unsigned short Bs[128 * 64];
  __shared__ float red[8];
  int m0 = blockIdx.x * 128, n0 = blockIdx.y * 128;
  int tid = threadIdx.x, w = tid >> 6, l = tid & 63;
  int wm = (w >> 1) * 64, wn = (w & 1) * 64;
  const int fcol = (l >> 4) * 8;
  f32x4 acc[4][4] = {};
  int nkt = K / 64;
  for (int kt = 0; kt < nkt; ++kt) {
    int k0 = kt * 64;
    __syncthreads();
#pragma unroll
    for (int it = 0; it < 4; ++it) {
      int eoff = (it * 256 + tid) * 8;
      int r = eoff >> 6, c = eoff & 63;
      GLDS16(A + (size_t)(m0 + r) * lda + (k0 + c), As + eoff);
      GLDS16(Bt + (size_t)(n0 + r) * ldb + (k0 + c), Bs + eoff);
    }
    __syncthreads();
#pragma unroll
    for (int kk = 0; kk < 2; ++kk) {
      s16x8 af[4], bfr[4];
#pragma unroll
      for (int f = 0; f < 4; ++f) {
        af[f]  = *(const s16x8*)&As[(wm + f * 16 + (l & 15)) * 64 + kk * 32 + fcol];
        bfr[f] = *(const s16x8*)&Bs[(wn + f * 16 + (l & 15)) * 64 + kk * 32 + fcol];
      }
#pragma unroll
      for (int i = 0; i < 4; ++i)
#pragma unroll
        for (int j = 0; j < 4; ++j)
          acc[i][j] = MFMA(af[i], bfr[j], acc[i][j]);
    }
  }
  float bsum = 0.f, bsq = 0.f;
#pragma unroll
  for (int i = 0; i < 4; ++i) {
    int rb = m0 + wm + i * 16 + (l >> 4) * 4;
#pragma unroll
    for (int j = 0; j < 4; ++j) {
      int col = n0 + wn + j * 16 + (l & 15);
      float bv = bias[col];
#pragma unroll
      for (int r4 = 0; r4 < 4; ++r4) {
        float v = acc[i][j][r4] + bv;
        size_t off = (size_t)(rb + r4) * ldc + col;
        if (MODE == 1) v = fmaxf(v, 0.f);
        if (MODE <= 1) {
          Cb[off] = f2bf(v);
        } else {
          v += resid[off];
          Cf[off] = v;
          bsum += v; bsq += v * v;
        }
      }
    }
  }
  if (MODE == 2) {
#pragma unroll
    for (int mk = 1; mk < 64; mk <<= 1) { bsum += __shfl_xor(bsum, mk); bsq += __shfl_xor(bsq, mk); }
    if (l == 0) { red[w] = bsum; red[4 + w] = bsq; }
    __syncthreads();
    if (tid == 0) {
      float s = red[0] + red[1] + red[2] + red[3];
      float q = red[4] + red[5] + red[6] + red[7];
      int b = m0 / rows_per_batch;
      int tpb = (rows_per_batch / 128) * n_tiles_n;
      int ti = ((int)blockIdx.x % (rows_per_batch / 128)) * n_tiles_n + (int)blockIdx.y;
      partials[(b * tpb + ti) * 2 + 0] = s;
      partials[(b * tpb + ti) * 2 + 1] = q;
    }
  }
}

// ---------------- V transpose per head: (s, d) -> (d, s), bf16 ----------------
__global__ __launch_bounds__(256) void k_transpose_v(const unsigned short* __restrict__ V, int ldv,
                                                     unsigned short* __restrict__ Vt, int S, int H) {
  __shared__ __align__(16) unsigned short t[64][72];
  int s0 = blockIdx.x * 64;
  int bh = blockIdx.y; int b = bh / H, h = bh % H;
  const unsigned short* src = V + (size_t)(b * S) * ldv + h * 64;
  unsigned short* dst = Vt + (size_t)bh * 64 * S;
  int tid = threadIdx.x;
#pragma unroll
  for (int i = 0; i < 2; ++i) {
    int idx = tid + i * 256;
    int s = idx >> 3, c = (idx & 7) * 8;
    s16x8 v = *(const s16x8*)(src + (size_t)(s0 + s) * ldv + c);
#pragma unroll
    for (int j = 0; j < 8; ++j) t[c + j][s] = (unsigned short)v[j];
  }
  __syncthreads();
#pragma unroll
  for (int i = 0; i < 2; ++i) {
    int idx = tid + i * 256;
    int d = idx >> 3, c = (idx & 7) * 8;
    *(s16x8*)(dst + (size_t)d * S + s0 + c) = *(const s16x8*)&t[d][c];
  }
}

// ---------------- causal flash attention + residual + LN partials ----------------
__global__ __launch_bounds__(256) void k_attn(
    const unsigned short* __restrict__ Qg, const unsigned short* __restrict__ Kg,
    const unsigned short* __restrict__ Vt, int ldqk,
    const float* __restrict__ x, float* __restrict__ hpre,
    float* __restrict__ partials, int S, int H) {
  __shared__ __align__(16) unsigned short Ks[64 * 64];
  __shared__ __align__(16) unsigned short Vs[64 * 64];
  __shared__ __align__(16) unsigned short Ps[4][16 * 64];
  __shared__ float red[8];
  int qt = blockIdx.x, bh = blockIdx.y, b = bh / H, h = bh % H;
  int tid = threadIdx.x, w = tid >> 6, l = tid & 63;
  const int U = H * 64;
  const unsigned short* Qb = Qg + (size_t)(b * S) * ldqk + h * 64;
  const unsigned short* Kb = Kg + (size_t)(b * S) * ldqk + h * 64;
  const unsigned short* Vb = Vt + (size_t)bh * 64 * S;
  int qrow = qt * 64 + w * 16 + (l & 15);
  s16x8 qf0 = *(const s16x8*)(Qb + (size_t)qrow * ldqk + (l >> 4) * 8);
  s16x8 qf1 = *(const s16x8*)(Qb + (size_t)qrow * ldqk + 32 + (l >> 4) * 8);
  f32x4 o[4] = {};
  float mrun[4] = {-1e30f, -1e30f, -1e30f, -1e30f};
  float lrun[4] = {0.f, 0.f, 0.f, 0.f};
  int qcd = qt * 64 + w * 16 + (l >> 4) * 4;  // C/D base row for this lane
  for (int kt = 0; kt <= qt; ++kt) {
    __syncthreads();
#pragma unroll
    for (int it = 0; it < 2; ++it) {
      int eoff = (it * 256 + tid) * 8;
      int r = eoff >> 6, c = eoff & 63;
      GLDS16(Kb + (size_t)(kt * 64 + r) * ldqk + c, Ks + eoff);
      GLDS16(Vb + (size_t)r * S + (kt * 64 + c), Vs + eoff);
    }
    __syncthreads();
    f32x4 sc[4];
#pragma unroll
    for (int fn = 0; fn < 4; ++fn) {
      s16x8 kf0 = *(const s16x8*)&Ks[(fn * 16 + (l & 15)) * 64 + (l >> 4) * 8];
      s16x8 kf1 = *(const s16x8*)&Ks[(fn * 16 + (l & 15)) * 64 + 32 + (l >> 4) * 8];
      f32x4 z = {};
      z = MFMA(qf0, kf0, z);
      z = MFMA(qf1, kf1, z);
      sc[fn] = z;
    }
#pragma unroll
    for (int fn = 0; fn < 4; ++fn) {
      int key = kt * 64 + fn * 16 + (l & 15);
#pragma unroll
      for (int j = 0; j < 4; ++j) {
        float v = sc[fn][j] * 0.125f;
        sc[fn][j] = (key > qcd + j) ? -1e30f : v;
      }
    }
#pragma unroll
    for (int j = 0; j < 4; ++j) {
      float mx = fmaxf(fmaxf(sc[0][j], sc[1][j]), fmaxf(sc[2][j], sc[3][j]));
#pragma unroll
      for (int mk = 1; mk < 16; mk <<= 1) mx = fmaxf(mx, __shfl_xor(mx, mk));
      float mnew = fmaxf(mrun[j], mx);
      float alpha = __expf(mrun[j] - mnew);
      float rs = 0.f;
#pragma unroll
      for (int fn = 0; fn < 4; ++fn) { float p = __expf(sc[fn][j] - mnew); sc[fn][j] = p; rs += p; }
#pragma unroll
      for (int mk = 1; mk < 16; mk <<= 1) rs += __shfl_xor(rs, mk);
      mrun[j] = mnew;
      lrun[j] = lrun[j] * alpha + rs;
#pragma unroll
      for (int fn = 0; fn < 4; ++fn) o[fn][j] *= alpha;
    }
    // P (C/D layout) -> LDS -> A layout
    unsigned short* Pw = &Ps[w][0];
#pragma unroll
    for (int fn = 0; fn < 4; ++fn)
#pragma unroll
      for (int j = 0; j < 4; ++j)
        Pw[((l >> 4) * 4 + j) * 64 + fn * 16 + (l & 15)] = f2bf(sc[fn][j]);
#pragma unroll
    for (int kk = 0; kk < 2; ++kk) {
      s16x8 pa = *(const s16x8*)&Pw[(l & 15) * 64 + kk * 32 + (l >> 4) * 8];
#pragma unroll
      for (int fd = 0; fd < 4; ++fd) {
        s16x8 vf = *(const s16x8*)&Vs[(fd * 16 + (l & 15)) * 64 + kk * 32 + (l >> 4) * 8];
        o[fd] = MFMA(pa, vf, o[fd]);
      }
    }
  }
  // epilogue: O/l + x residual, write hpre, LN partial sums
  float bsum = 0.f, bsq = 0.f;
  const float* xb = x + (size_t)(b * S) * U + h * 64;
  float* hb = hpre + (size_t)(b * S) * U + h * 64;
#pragma unroll
  for (int fd = 0; fd < 4; ++fd) {
    int col = fd * 16 + (l & 15);
#pragma unroll
    for (int j = 0; j < 4; ++j) {
      int row = qcd + j;
      float v = o[fd][j] / lrun[j] + xb[(size_t)row * U + col];
      hb[(size_t)row * U + col] = v;
      bsum += v; bsq += v * v;
    }
  }
#pragma unroll
  for (int mk = 1; mk < 64; mk <<= 1) { bsum += __shfl_xor(bsum, mk); bsq += __shfl_xor(bsq, mk); }
  if (l == 0) { red[w] = bsum; red[4 + w] = bsq; }
  __syncthreads();
  if (tid == 0) {
    float s2 = red[0] + red[1] + red[2] + red[3];
    float q2 = red[4] + red[5] + red[6] + red[7];
    int nqt = S / 64;
    int pi = b * (H * nqt) + h * nqt + qt;
    partials[pi * 2] = s2; partials[pi * 2 + 1] = q2;
  }
}

// ---------------- LN over (S,U) per batch: stats from partials ----------------
__global__ __launch_bounds__(256) void k_ln_stats(const float* __restrict__ partials, int nper,
                                                  float* __restrict__ stats, float invN) {
  int b = blockIdx.x, tid = threadIdx.x;
  float s = 0.f, q = 0.f;
  for (int i = tid; i < nper; i += 256) { s += partials[(b * nper + i) * 2]; q += partials[(b * nper + i) * 2 + 1]; }
#pragma unroll
  for (int mk = 1; mk < 64; mk <<= 1) { s += __shfl_xor(s, mk); q += __shfl_xor(q, mk); }
  __shared__ float red[8];
  int w = tid >> 6, l = tid & 63;
  if (l == 0) { red[w] = s; red[4 + w] = q; }
  __syncthreads();
  if (tid == 0) {
    s = red[0] + red[1] + red[2] + red[3];
    q = red[4] + red[5] + red[6] + red[7];
    float m = s * invN, var = q * invN - m * m;
    stats[b * 2] = m; stats[b * 2 + 1] = rsqrtf(var + 1e-5f);
  }
}

__global__ __launch_bounds__(256) void k_ln_apply(
    const float* __restrict__ src, const float* __restrict__ stats,
    const float* __restrict__ g, const float* __restrict__ bt,
    float* __restrict__ outf, unsigned short* __restrict__ outb, int SU) {
  int b = blockIdx.y;
  int idx = (blockIdx.x * 256 + threadIdx.x) * 4;
  float m = stats[b * 2], r = stats[b * 2 + 1];
  float4 v = *(const float4*)(src + (size_t)b * SU + idx);
  float4 gg = *(const float4*)(g + idx);
  float4 bb = *(const float4*)(bt + idx);
  float4 o;
  o.x = (v.x - m) * r * gg.x + bb.x;
  o.y = (v.y - m) * r * gg.y + bb.y;
  o.z = (v.z - m) * r * gg.z + bb.z;
  o.w = (v.w - m) * r * gg.w + bb.w;
  *(float4*)(outf + (size_t)b * SU + idx) = o;
  if (outb) {
    u16x4 ob; ob.x = f2bf(o.x); ob.y = f2bf(o.y); ob.z = f2bf(o.z); ob.w = f2bf(o.w);
    *(u16x4*)(outb + (size_t)b * SU + idx) = ob;
  }
}

extern "C" void kernel_launch(void* const* d_in, const int* in_sizes, int n_in,
                              void* d_out, int out_size, void* d_ws, size_t ws_size,
                              hipStream_t stream) {
  (void)in_sizes; (void)n_in; (void)out_size; (void)ws_size;
  const int S = 2048, H = 16;
  const float* x   = (const float*)d_in[0];
  const float* wq  = (const float*)d_in[1];
  const float* bq  = (const float*)d_in[2];
  const float* wk  = (const float*)d_in[3];
  const float* bk  = (const float*)d_in[4];
  const float* wv  = (const float*)d_in[5];
  const float* bv  = (const float*)d_in[6];
  const float* wf1 = (const float*)d_in[7];
  const float* bf1 = (const float*)d_in[8];
  const float* wf2 = (const float*)d_in[9];
  const float* bf2 = (const float*)d_in[10];
  const float* lng = (const float*)d_in[11];
  const float* lnb = (const float*)d_in[12];
  const float* ffg = (const float*)d_in[13];
  const float* ffb = (const float*)d_in[14];

  char* ws = (char*)d_ws;
  unsigned short* wqkvT = (unsigned short*)(ws);              // 3072x1024 bf16  (6 MB)
  unsigned short* wf1T  = (unsigned short*)(ws + 6291456);    // 4096x1024 bf16  (8 MB)
  unsigned short* wf2T  = (unsigned short*)(ws + 14680064);   // 1024x4096 bf16  (8 MB)
  unsigned short* xb    = (unsigned short*)(ws + 23068672);   // 4096x1024 bf16  (8 MB)
  unsigned short* qkv   = (unsigned short*)(ws + 31457280);   // 4096x3072 bf16  (24 MB)
  unsigned short* vt    = (unsigned short*)(ws + 56623104);   // 32 x 64 x 2048 bf16 (8 MB)
  float* hpre           = (float*)(ws + 65011712);            // 4096x1024 f32 (16 MB, reused for h2pre)
  float* h1             = (float*)(ws + 81788928);            // 4096x1024 f32 (16 MB)
  unsigned short* h1b   = (unsigned short*)(ws + 98566144);   // 4096x1024 bf16 (8 MB)
  unsigned short* f1b   = (unsigned short*)(ws + 23068672);   // 4096x4096 bf16 (32 MB, reuses xb+qkv)
  float* biasqkv        = (float*)(ws + 106954752);           // 3072 f32
  float* part1          = (float*)(ws + 106967040);           // 2*512*2 f32
  float* part2          = (float*)(ws + 106975232);           // 2*128*2 f32
  float* stats1         = (float*)(ws + 106977280);           // 4 f32
  float* stats2         = (float*)(ws + 106977344);           // 4 f32

  // 1. conversions / transposes
  k_f32_to_bf16<<<4096, 256, 0, stream>>>(x, xb, 4096 * 1024 / 4);
  k_transpose_w<<<dim3(16, 16), 256, 0, stream>>>(wq, wqkvT, 1024, 1024);
  k_transpose_w<<<dim3(16, 16), 256, 0, stream>>>(wk, wqkvT + 1024 * 1024, 1024, 1024);
  k_transpose_w<<<dim3(16, 16), 256, 0, stream>>>(wv, wqkvT + 2048 * 1024, 1024, 1024);
  k_transpose_w<<<dim3(16, 64), 256, 0, stream>>>(wf1, wf1T, 1024, 4096);
  k_transpose_w<<<dim3(64, 16), 256, 0, stream>>>(wf2, wf2T, 4096, 1024);
  k_concat3<<<12, 256, 0, stream>>>(bq, bk, bv, biasqkv, 1024);

  // 2. fused QKV projection: (4096x1024) @ (1024x3072)
  k_gemm<0><<<dim3(32, 24), 256, 0, stream>>>(xb, 1024, wqkvT, 1024, biasqkv,
      qkv, nullptr, 3072, nullptr, nullptr, 1024, 2048, 24);

  // 3. V transpose per head
  k_transpose_v<<<dim3(32, 32), 256, 0, stream>>>(qkv + 2048, 3072, vt, S, H);

  // 4. causal flash attention + x residual + LN1 partials
  k_attn<<<dim3(32, 32), 256, 0, stream>>>(qkv, qkv + 1024, vt, 3072, x, hpre, part1, S, H);

  // 5. LN1
  k_ln_stats<<<2, 256, 0, stream>>>(part1, 512, stats1, 1.f / (2048.f * 1024.f));
  k_ln_apply<<<dim3(2048, 2), 256, 0, stream>>>(hpre, stats1, lng, lnb, h1, h1b, S * 1024);

  // 6. FF1: (4096x1024) @ (1024x4096), ReLU
  k_gemm<1><<<dim3(32, 32), 256, 0, stream>>>(h1b, 1024, wf1T, 1024, bf1,
      f1b, nullptr, 4096, nullptr, nullptr, 1024, 2048, 32);

  // 7. FF2: (4096x4096) @ (4096x1024) + h1 residual + LN2 partials
  k_gemm<2><<<dim3(32, 8), 256, 0, stream>>>(f1b, 4096, wf2T, 4096, bf2,
      nullptr, hpre, 1024, h1, part2, 4096, 2048, 8);

  // 8. LN2 -> d_out (fp32)
  k_ln_stats<<<2, 256, 0, stream>>>(part2, 128, stats2, 1.f / (2048.f * 1024.f));
  k_ln_apply<<<dim3(2048, 2), 256, 0, stream>>>(hpre, stats2, ffg, ffb, (float*)d_out, nullptr, S * 1024);
}

// Round 2
// 315.576 us; speedup vs baseline: 1.2616x; 1.2616x over previous
//
#include <hip/hip_runtime.h>

typedef short s16x8 __attribute__((ext_vector_type(8)));
typedef float f32x4 __attribute__((ext_vector_type(4)));
typedef unsigned short u16x4 __attribute__((ext_vector_type(4)));

#define DEV static __device__ __forceinline__

DEV unsigned short f2bf(float f) {
  union { float f; unsigned u; } v; v.f = f;
  unsigned r = v.u + 0x7FFFu + ((v.u >> 16) & 1u);
  return (unsigned short)(r >> 16);
}

#define GLDS16(src, dst) \
  __builtin_amdgcn_global_load_lds((const __attribute__((address_space(1))) void*)(src), \
                                   (__attribute__((address_space(3))) void*)(dst), 16, 0, 0)

#define MFMA(a, b, c) __builtin_amdgcn_mfma_f32_16x16x32_bf16((a), (b), (c), 0, 0, 0)

// ---------------- elementwise fp32 -> bf16 ----------------
__global__ __launch_bounds__(256) void k_f32_to_bf16(const float* __restrict__ in,
                                                     unsigned short* __restrict__ out, int n4) {
  int i = blockIdx.x * 256 + threadIdx.x;
  if (i >= n4) return;
  float4 v = ((const float4*)in)[i];
  u16x4 o; o.x = f2bf(v.x); o.y = f2bf(v.y); o.z = f2bf(v.z); o.w = f2bf(v.w);
  ((u16x4*)out)[i] = o;
}

// ---------------- weight transpose+convert: (K,N) f32 -> (N,K) bf16, with scale ----------------
__global__ __launch_bounds__(256) void k_transpose_w(const float* __restrict__ W,
                                                     unsigned short* __restrict__ Wt,
                                                     int K, int N, float scale) {
  __shared__ float t[64][65];
  int k0 = blockIdx.x * 64, n0 = blockIdx.y * 64;
  int tid = threadIdx.x;
#pragma unroll
  for (int i = 0; i < 16; ++i) {
    int idx = tid + i * 256; int r = idx >> 6, c = idx & 63;
    t[r][c] = W[(size_t)(k0 + r) * N + (n0 + c)];
  }
  __syncthreads();
#pragma unroll
  for (int i = 0; i < 16; ++i) {
    int idx = tid + i * 256; int r = idx >> 6, c = idx & 63;
    Wt[(size_t)(n0 + r) * K + (k0 + c)] = f2bf(t[c][r] * scale);
  }
}

// ---------------- concat 3 bias vectors (a gets scale) ----------------
__global__ void k_concat3(const float* __restrict__ a, const float* __restrict__ b,
                          const float* __restrict__ c, float* __restrict__ out, int n, float sa) {
  int i = blockIdx.x * 256 + threadIdx.x;
  if (i >= 3 * n) return;
  int j = (i < n) ? i : (i < 2 * n ? i - n : i - 2 * n);
  out[i] = (i < n) ? a[j] * sa : (i < 2 * n ? b[j] : c[j]);
}

// ---------------- GEMM: C = A(MxK) * Bt(NxK)^T + bias ----------------
// MODE 0: bf16 out. MODE 1: bf16 out + relu. MODE 2: f32 out + residual + LN partials.
template <int MODE>
__global__ __launch_bounds__(256) void k_gemm(
    const unsigned short* __restrict__ A, int lda,
    const unsigned short* __restrict__ Bt, int ldb,
    const float* __restrict__ bias,
    unsigned short* __restrict__ Cb, float* __restrict__ Cf, int ldc,
    const float* __restrict__ resid, float* __restrict__ partials,
    int K, int rows_per_batch, int n_tiles_n) {
  __shared__ __align__(16) unsigned short As[128 * 64];
  __shared__ __align__(16) unsigned short Bs[128 * 64];
  __shared__ float red[8];
  int m0 = blockIdx.x * 128, n0 = blockIdx.y * 128;
  int tid = threadIdx.x, w = tid >> 6, l = tid & 63;
  int wm = (w >> 1) * 64, wn = (w & 1) * 64;
  const int fcol = (l >> 4) * 8;
  f32x4 acc[4][4] = {};
  int nkt = K / 64;
  for (int kt = 0; kt < nkt; ++kt) {
    int k0 = kt * 64;
    __syncthreads();
#pragma unroll
    for (int it = 0; it < 4; ++it) {
      int eoff = (it * 256 + tid) * 8;
      int r = eoff >> 6, c = eoff & 63;
      GLDS16(A + (size_t)(m0 + r) * lda + (k0 + c), As + eoff);
      GLDS16(Bt + (size_t)(n0 + r) * ldb + (k0 + c), Bs + eoff);
    }
    __syncthreads();
#pragma unroll
    for (int kk = 0; kk < 2; ++kk) {
      s16x8 af[4], bfr[4];
#pragma unroll
      for (int f = 0; f < 4; ++f) {
        af[f]  = *(const s16x8*)&As[(wm + f * 16 + (l & 15)) * 64 + kk * 32 + fcol];
        bfr[f] = *(const s16x8*)&Bs[(wn + f * 16 + (l & 15)) * 64 + kk * 32 + fcol];
      }
#pragma unroll
      for (int i = 0; i < 4; ++i)
#pragma unroll
        for (int j = 0; j < 4; ++j)
          acc[i][j] = MFMA(af[i], bfr[j], acc[i][j]);
    }
  }
  float bsum = 0.f, bsq = 0.f;
#pragma unroll
  for (int i = 0; i < 4; ++i) {
    int rb = m0 + wm + i * 16 + (l >> 4) * 4;
#pragma unroll
    for (int j = 0; j < 4; ++j) {
      int col = n0 + wn + j * 16 + (l & 15);
      float bv = bias[col];
#pragma unroll
      for (int r4 = 0; r4 < 4; ++r4) {
        float v = acc[i][j][r4] + bv;
        size_t off = (size_t)(rb + r4) * ldc + col;
        if (MODE == 1) v = fmaxf(v, 0.f);
        if (MODE <= 1) {
          Cb[off] = f2bf(v);
        } else {
          v += resid[off];
          Cf[off] = v;
          bsum += v; bsq += v * v;
        }
      }
    }
  }
  if (MODE == 2) {
#pragma unroll
    for (int mk = 1; mk < 64; mk <<= 1) { bsum += __shfl_xor(bsum, mk); bsq += __shfl_xor(bsq, mk); }
    if (l == 0) { red[w] = bsum; red[4 + w] = bsq; }
    __syncthreads();
    if (tid == 0) {
      float s = red[0] + red[1] + red[2] + red[3];
      float q = red[4] + red[5] + red[6] + red[7];
      int b = m0 / rows_per_batch;
      int tpb = (rows_per_batch / 128) * n_tiles_n;
      int ti = ((int)blockIdx.x % (rows_per_batch / 128)) * n_tiles_n + (int)blockIdx.y;
      partials[(b * tpb + ti) * 2 + 0] = s;
      partials[(b * tpb + ti) * 2 + 1] = q;
    }
  }
}

// ---------------- V transpose per head: (s, d) -> (d, s), bf16 ----------------
__global__ __launch_bounds__(256) void k_transpose_v(const unsigned short* __restrict__ V, int ldv,
                                                     unsigned short* __restrict__ Vt, int S, int H) {
  __shared__ __align__(16) unsigned short t[64][72];
  int s0 = blockIdx.x * 64;
  int bh = blockIdx.y; int b = bh / H, h = bh % H;
  const unsigned short* src = V + (size_t)(b * S) * ldv + h * 64;
  unsigned short* dst = Vt + (size_t)bh * 64 * S;
  int tid = threadIdx.x;
#pragma unroll
  for (int i = 0; i < 2; ++i) {
    int idx = tid + i * 256;
    int s = idx >> 3, c = (idx & 7) * 8;
    s16x8 v = *(const s16x8*)(src + (size_t)(s0 + s) * ldv + c);
#pragma unroll
    for (int j = 0; j < 8; ++j) t[c + j][s] = (unsigned short)v[j];
  }
  __syncthreads();
#pragma unroll
  for (int i = 0; i < 2; ++i) {
    int idx = tid + i * 256;
    int d = idx >> 3, c = (idx & 7) * 8;
    *(s16x8*)(dst + (size_t)d * S + s0 + c) = *(const s16x8*)&t[d][c];
  }
}

// ---------------- causal flash attention + residual + LN partials ----------------
// Swizzled LDS (el ^= (row&7)*8 on 8-elem granules), double-buffered K/V with
// prefetch (1 barrier/tile), q-tile pairing (i, nqt-1-i) for load balance.
__global__ __launch_bounds__(256) void k_attn(
    const unsigned short* __restrict__ Qg, const unsigned short* __restrict__ Kg,
    const unsigned short* __restrict__ Vt, int ldqk,
    const float* __restrict__ x, float* __restrict__ hpre,
    float* __restrict__ partials, int S, int H) {
  __shared__ __align__(16) unsigned short Ks[2][64 * 64];
  __shared__ __align__(16) unsigned short Vs[2][64 * 64];
  __shared__ __align__(16) unsigned short Ps[4][16 * 64];
  __shared__ float red[8];
  int bh = blockIdx.y, b = bh / H, h = bh % H;
  int tid = threadIdx.x, w = tid >> 6, l = tid & 63;
  const int U = H * 64;
  const int nqt = S / 64;
  const unsigned short* Qb = Qg + (size_t)(b * S) * ldqk + h * 64;
  const unsigned short* Kb = Kg + (size_t)(b * S) * ldqk + h * 64;
  const unsigned short* Vb = Vt + (size_t)bh * 64 * S;
  const float* xb = x + (size_t)(b * S) * U + h * 64;
  float* hb = hpre + (size_t)(b * S) * U + h * 64;
  // staging coords: granule g = it*256+tid; dest is linear (lane*16 within wave);
  // source column granule pre-swizzled so LDS content matches swizzled reads.
  int sg_r[2], sg_c[2];
#pragma unroll
  for (int it = 0; it < 2; ++it) {
    int g = it * 256 + tid;
    sg_r[it] = g >> 3;
    sg_c[it] = ((g & 7) ^ ((g >> 3) & 7)) * 8;
  }
  unsigned short* Pw = &Ps[w][0];

  for (int pass = 0; pass < 2; ++pass) {
    int qt = (pass == 0) ? (int)blockIdx.x : (nqt - 1 - (int)blockIdx.x);
    int qrow = qt * 64 + w * 16 + (l & 15);
    s16x8 qf0 = *(const s16x8*)(Qb + (size_t)qrow * ldqk + (l >> 4) * 8);
    s16x8 qf1 = *(const s16x8*)(Qb + (size_t)qrow * ldqk + 32 + (l >> 4) * 8);
    f32x4 o[4] = {};
    float mrun[4] = {-1e30f, -1e30f, -1e30f, -1e30f};
    float lrun[4] = {0.f, 0.f, 0.f, 0.f};
    int qcd = qt * 64 + w * 16 + (l >> 4) * 4;  // C/D base row for this lane

    // prologue stage tile 0 -> buf 0
#pragma unroll
    for (int it = 0; it < 2; ++it) {
      GLDS16(Kb + (size_t)sg_r[it] * ldqk + sg_c[it], &Ks[0][(it * 256 + tid) * 8]);
      GLDS16(Vb + (size_t)sg_r[it] * S + sg_c[it], &Vs[0][(it * 256 + tid) * 8]);
    }

    for (int kt = 0; kt <= qt; ++kt) {
      int cur = kt & 1;
      __syncthreads();  // drains vmcnt(0): stage(kt) complete; prev-tile reads done
      if (kt < qt) {
        int nb = cur ^ 1, kn = (kt + 1) * 64;
#pragma unroll
        for (int it = 0; it < 2; ++it) {
          GLDS16(Kb + (size_t)(kn + sg_r[it]) * ldqk + sg_c[it], &Ks[nb][(it * 256 + tid) * 8]);
          GLDS16(Vb + (size_t)sg_r[it] * S + kn + sg_c[it], &Vs[nb][(it * 256 + tid) * 8]);
        }
      }
      // ---- QK^T (swizzled K reads: conflict-free) ----
      f32x4 sc[4];
      __builtin_amdgcn_s_setprio(1);
#pragma unroll
      for (int fn = 0; fn < 4; ++fn) {
        int row = fn * 16 + (l & 15);
        int r7 = (row & 7) * 8;
        s16x8 kf0 = *(const s16x8*)&Ks[cur][row * 64 + ((((l >> 4)) ^ (row & 7)) * 8)];
        s16x8 kf1 = *(const s16x8*)&Ks[cur][row * 64 + (((4 + (l >> 4)) ^ (row & 7)) * 8)];
        (void)r7;
        f32x4 z = {};
        z = MFMA(qf0, kf0, z);
        z = MFMA(qf1, kf1, z);
        sc[fn] = z;
      }
      __builtin_amdgcn_s_setprio(0);
      // ---- mask (diagonal tile only; scale pre-folded into Q) ----
      if (kt == qt) {
#pragma unroll
        for (int fn = 0; fn < 4; ++fn) {
          int key = kt * 64 + fn * 16 + (l & 15);
#pragma unroll
          for (int j = 0; j < 4; ++j)
            sc[fn][j] = (key > qcd + j) ? -1e30f : sc[fn][j];
        }
      }
      // ---- online softmax ----
#pragma unroll
      for (int j = 0; j < 4; ++j) {
        float mx = fmaxf(fmaxf(sc[0][j], sc[1][j]), fmaxf(sc[2][j], sc[3][j]));
#pragma unroll
        for (int mk = 1; mk < 16; mk <<= 1) mx = fmaxf(mx, __shfl_xor(mx, mk));
        float mnew = fmaxf(mrun[j], mx);
        float alpha = __expf(mrun[j] - mnew);
        float rs = 0.f;
#pragma unroll
        for (int fn = 0; fn < 4; ++fn) { float p = __expf(sc[fn][j] - mnew); sc[fn][j] = p; rs += p; }
#pragma unroll
        for (int mk = 1; mk < 16; mk <<= 1) rs += __shfl_xor(rs, mk);
        mrun[j] = mnew;
        lrun[j] = lrun[j] * alpha + rs;
#pragma unroll
        for (int fn = 0; fn < 4; ++fn) o[fn][j] *= alpha;
      }
      // ---- P (C/D layout) -> LDS (swizzled) -> A layout ----
#pragma unroll
      for (int fn = 0; fn < 4; ++fn)
#pragma unroll
        for (int j = 0; j < 4; ++j) {
          int row = (l >> 4) * 4 + j;
          int col = fn * 16 + (l & 15);
          Pw[row * 64 + (col ^ ((row & 7) * 8))] = f2bf(sc[fn][j]);
        }
      __builtin_amdgcn_s_setprio(1);
#pragma unroll
      for (int kk = 0; kk < 2; ++kk) {
        int prow = l & 15;
        s16x8 pa = *(const s16x8*)&Pw[prow * 64 + (((kk * 4 + (l >> 4)) ^ (prow & 7)) * 8)];
#pragma unroll
        for (int fd = 0; fd < 4; ++fd) {
          int vrow = fd * 16 + (l & 15);
          s16x8 vf = *(const s16x8*)&Vs[cur][vrow * 64 + (((kk * 4 + (l >> 4)) ^ (vrow & 7)) * 8)];
          o[fd] = MFMA(pa, vf, o[fd]);
        }
      }
      __builtin_amdgcn_s_setprio(0);
    }
    // ---- epilogue: O/l + x residual, write hpre, LN partial sums ----
    float bsum = 0.f, bsq = 0.f;
#pragma unroll
    for (int fd = 0; fd < 4; ++fd) {
      int col = fd * 16 + (l & 15);
#pragma unroll
      for (int j = 0; j < 4; ++j) {
        int row = qcd + j;
        float v = o[fd][j] / lrun[j] + xb[(size_t)row * U + col];
        hb[(size_t)row * U + col] = v;
        bsum += v; bsq += v * v;
      }
    }
#pragma unroll
    for (int mk = 1; mk < 64; mk <<= 1) { bsum += __shfl_xor(bsum, mk); bsq += __shfl_xor(bsq, mk); }
    if (l == 0) { red[w] = bsum; red[4 + w] = bsq; }
    __syncthreads();
    if (tid == 0) {
      float s2 = red[0] + red[1] + red[2] + red[3];
      float q2 = red[4] + red[5] + red[6] + red[7];
      int pi = b * (H * nqt) + h * nqt + qt;
      partials[pi * 2] = s2; partials[pi * 2 + 1] = q2;
    }
    __syncthreads();  // red[] reuse + LDS buffer safety before next pass's stage
  }
}

// ---------------- LN over (S,U) per batch: stats from partials ----------------
__global__ __launch_bounds__(256) void k_ln_stats(const float* __restrict__ partials, int nper,
                                                  float* __restrict__ stats, float invN) {
  int b = blockIdx.x, tid = threadIdx.x;
  float s = 0.f, q = 0.f;
  for (int i = tid; i < nper; i += 256) { s += partials[(b * nper + i) * 2]; q += partials[(b * nper + i) * 2 + 1]; }
#pragma unroll
  for (int mk = 1; mk < 64; mk <<= 1) { s += __shfl_xor(s, mk); q += __shfl_xor(q, mk); }
  __shared__ float red[8];
  int w = tid >> 6, l = tid & 63;
  if (l == 0) { red[w] = s; red[4 + w] = q; }
  __syncthreads();
  if (tid == 0) {
    s = red[0] + red[1] + red[2] + red[3];
    q = red[4] + red[5] + red[6] + red[7];
    float m = s * invN, var = q * invN - m * m;
    stats[b * 2] = m; stats[b * 2 + 1] = rsqrtf(var + 1e-5f);
  }
}

__global__ __launch_bounds__(256) void k_ln_apply(
    const float* __restrict__ src, const float* __restrict__ stats,
    const float* __restrict__ g, const float* __restrict__ bt,
    float* __restrict__ outf, unsigned short* __restrict__ outb, int SU) {
  int b = blockIdx.y;
  int idx = (blockIdx.x * 256 + threadIdx.x) * 4;
  float m = stats[b * 2], r = stats[b * 2 + 1];
  float4 v = *(const float4*)(src + (size_t)b * SU + idx);
  float4 gg = *(const float4*)(g + idx);
  float4 bb = *(const float4*)(bt + idx);
  float4 o;
  o.x = (v.x - m) * r * gg.x + bb.x;
  o.y = (v.y - m) * r * gg.y + bb.y;
  o.z = (v.z - m) * r * gg.z + bb.z;
  o.w = (v.w - m) * r * gg.w + bb.w;
  *(float4*)(outf + (size_t)b * SU + idx) = o;
  if (outb) {
    u16x4 ob; ob.x = f2bf(o.x); ob.y = f2bf(o.y); ob.z = f2bf(o.z); ob.w = f2bf(o.w);
    *(u16x4*)(outb + (size_t)b * SU + idx) = ob;
  }
}

extern "C" void kernel_launch(void* const* d_in, const int* in_sizes, int n_in,
                              void* d_out, int out_size, void* d_ws, size_t ws_size,
                              hipStream_t stream) {
  (void)in_sizes; (void)n_in; (void)out_size; (void)ws_size;
  const int S = 2048, H = 16;
  const float* x   = (const float*)d_in[0];
  const float* wq  = (const float*)d_in[1];
  const float* bq  = (const float*)d_in[2];
  const float* wk  = (const float*)d_in[3];
  const float* bk  = (const float*)d_in[4];
  const float* wv  = (const float*)d_in[5];
  const float* bv  = (const float*)d_in[6];
  const float* wf1 = (const float*)d_in[7];
  const float* bf1 = (const float*)d_in[8];
  const float* wf2 = (const float*)d_in[9];
  const float* bf2 = (const float*)d_in[10];
  const float* lng = (const float*)d_in[11];
  const float* lnb = (const float*)d_in[12];
  const float* ffg = (const float*)d_in[13];
  const float* ffb = (const float*)d_in[14];

  char* ws = (char*)d_ws;
  unsigned short* wqkvT = (unsigned short*)(ws);              // 3072x1024 bf16  (6 MB)
  unsigned short* wf1T  = (unsigned short*)(ws + 6291456);    // 4096x1024 bf16  (8 MB)
  unsigned short* wf2T  = (unsigned short*)(ws + 14680064);   // 1024x4096 bf16  (8 MB)
  unsigned short* xb    = (unsigned short*)(ws + 23068672);   // 4096x1024 bf16  (8 MB)
  unsigned short* qkv   = (unsigned short*)(ws + 31457280);   // 4096x3072 bf16  (24 MB)
  unsigned short* vt    = (unsigned short*)(ws + 56623104);   // 32 x 64 x 2048 bf16 (8 MB)
  float* hpre           = (float*)(ws + 65011712);            // 4096x1024 f32 (16 MB, reused for h2pre)
  float* h1             = (float*)(ws + 81788928);            // 4096x1024 f32 (16 MB)
  unsigned short* h1b   = (unsigned short*)(ws + 98566144);   // 4096x1024 bf16 (8 MB)
  unsigned short* f1b   = (unsigned short*)(ws + 23068672);   // 4096x4096 bf16 (32 MB, reuses xb+qkv)
  float* biasqkv        = (float*)(ws + 106954752);           // 3072 f32
  float* part1          = (float*)(ws + 106967040);           // 2*512*2 f32
  float* part2          = (float*)(ws + 106975232);           // 2*128*2 f32
  float* stats1         = (float*)(ws + 106977280);           // 4 f32
  float* stats2         = (float*)(ws + 106977344);           // 4 f32

  // 1. conversions / transposes (Q path pre-scaled by 1/sqrt(dh)=0.125)
  k_f32_to_bf16<<<4096, 256, 0, stream>>>(x, xb, 4096 * 1024 / 4);
  k_transpose_w<<<dim3(16, 16), 256, 0, stream>>>(wq, wqkvT, 1024, 1024, 0.125f);
  k_transpose_w<<<dim3(16, 16), 256, 0, stream>>>(wk, wqkvT + 1024 * 1024, 1024, 1024, 1.0f);
  k_transpose_w<<<dim3(16, 16), 256, 0, stream>>>(wv, wqkvT + 2048 * 1024, 1024, 1024, 1.0f);
  k_transpose_w<<<dim3(16, 64), 256, 0, stream>>>(wf1, wf1T, 1024, 4096, 1.0f);
  k_transpose_w<<<dim3(64, 16), 256, 0, stream>>>(wf2, wf2T, 4096, 1024, 1.0f);
  k_concat3<<<12, 256, 0, stream>>>(bq, bk, bv, biasqkv, 1024, 0.125f);

  // 2. fused QKV projection: (4096x1024) @ (1024x3072)
  k_gemm<0><<<dim3(32, 24), 256, 0, stream>>>(xb, 1024, wqkvT, 1024, biasqkv,
      qkv, nullptr, 3072, nullptr, nullptr, 1024, 2048, 24);

  // 3. V transpose per head
  k_transpose_v<<<dim3(32, 32), 256, 0, stream>>>(qkv + 2048, 3072, vt, S, H);

  // 4. causal flash attention + x residual + LN1 partials (paired q-tiles)
  k_attn<<<dim3(16, 32), 256, 0, stream>>>(qkv, qkv + 1024, vt, 3072, x, hpre, part1, S, H);

  // 5. LN1
  k_ln_stats<<<2, 256, 0, stream>>>(part1, 512, stats1, 1.f / (2048.f * 1024.f));
  k_ln_apply<<<dim3(2048, 2), 256, 0, stream>>>(hpre, stats1, lng, lnb, h1, h1b, S * 1024);

  // 6. FF1: (4096x1024) @ (1024x4096), ReLU
  k_gemm<1><<<dim3(32, 32), 256, 0, stream>>>(h1b, 1024, wf1T, 1024, bf1,
      f1b, nullptr, 4096, nullptr, nullptr, 1024, 2048, 32);

  // 7. FF2: (4096x4096) @ (4096x1024) + h1 residual + LN2 partials
  k_gemm<2><<<dim3(32, 8), 256, 0, stream>>>(f1b, 4096, wf2T, 4096, bf2,
      nullptr, hpre, 1024, h1, part2, 4096, 2048, 8);

  // 8. LN2 -> d_out (fp32)
  k_ln_stats<<<2, 256, 0, stream>>>(part2, 128, stats2, 1.f / (2048.f * 1024.f));
  k_ln_apply<<<dim3(2048, 2), 256, 0, stream>>>(hpre, stats2, ffg, ffb, (float*)d_out, nullptr, S * 1024);
}

// Round 3
// 307.451 us; speedup vs baseline: 1.2949x; 1.0264x over previous
//
#include <hip/hip_runtime.h>

typedef short s16x8 __attribute__((ext_vector_type(8)));
typedef float f32x4 __attribute__((ext_vector_type(4)));
typedef unsigned short u16x4 __attribute__((ext_vector_type(4)));

#define DEV static __device__ __forceinline__

DEV unsigned short f2bf(float f) {
  union { float f; unsigned u; } v; v.f = f;
  unsigned r = v.u + 0x7FFFu + ((v.u >> 16) & 1u);
  return (unsigned short)(r >> 16);
}
DEV float bf2f(unsigned short u) {
  union { unsigned u; float f; } v; v.u = (unsigned)u << 16; return v.f;
}

#define GLDS16(src, dst) \
  __builtin_amdgcn_global_load_lds((const __attribute__((address_space(1))) void*)(src), \
                                   (__attribute__((address_space(3))) void*)(dst), 16, 0, 0)

#define MFMA(a, b, c) __builtin_amdgcn_mfma_f32_16x16x32_bf16((a), (b), (c), 0, 0, 0)

// ---------------- elementwise fp32 -> bf16 ----------------
__global__ __launch_bounds__(256) void k_f32_to_bf16(const float* __restrict__ in,
                                                     unsigned short* __restrict__ out, int n4) {
  int i = blockIdx.x * 256 + threadIdx.x;
  if (i >= n4) return;
  float4 v = ((const float4*)in)[i];
  u16x4 o; o.x = f2bf(v.x); o.y = f2bf(v.y); o.z = f2bf(v.z); o.w = f2bf(v.w);
  ((u16x4*)out)[i] = o;
}

// ---------------- weight transpose+convert: (K,N) f32 -> (N,K) bf16, with scale ----------------
__global__ __launch_bounds__(256) void k_transpose_w(const float* __restrict__ W,
                                                     unsigned short* __restrict__ Wt,
                                                     int K, int N, float scale) {
  __shared__ float t[64][65];
  int k0 = blockIdx.x * 64, n0 = blockIdx.y * 64;
  int tid = threadIdx.x;
#pragma unroll
  for (int i = 0; i < 16; ++i) {
    int idx = tid + i * 256; int r = idx >> 6, c = idx & 63;
    t[r][c] = W[(size_t)(k0 + r) * N + (n0 + c)];
  }
  __syncthreads();
#pragma unroll
  for (int i = 0; i < 16; ++i) {
    int idx = tid + i * 256; int r = idx >> 6, c = idx & 63;
    Wt[(size_t)(n0 + r) * K + (k0 + c)] = f2bf(t[c][r] * scale);
  }
}

// ---------------- concat 3 bias vectors (a gets scale) ----------------
__global__ void k_concat3(const float* __restrict__ a, const float* __restrict__ b,
                          const float* __restrict__ c, float* __restrict__ out, int n, float sa) {
  int i = blockIdx.x * 256 + threadIdx.x;
  if (i >= 3 * n) return;
  int j = (i < n) ? i : (i < 2 * n ? i - n : i - 2 * n);
  out[i] = (i < n) ? a[j] * sa : (i < 2 * n ? b[j] : c[j]);
}

// ---------------- 256x256 pipelined GEMM: C = A(MxK) * Bt(NxK)^T ----------------
// BK=32, 4-deep LDS ring (128 KiB), 8 waves (2Mx4N), counted vmcnt (never 0 in
// main loop), XOR-swizzled LDS (granule ^= (row>>1)&3, both-sides via
// pre-swizzled global source), setprio around MFMA clusters, XCD block swizzle.
// MODE 0: bias -> bf16. MODE 1: bias+relu -> bf16. MODE 3: raw f32 partial
// (no bias) at Cf + blockIdx.z*zstride, K is per-slice length.
template <int MODE>
__global__ __launch_bounds__(512, 2) void k_gemm8(
    const unsigned short* __restrict__ A, int lda,
    const unsigned short* __restrict__ Bt, int ldb,
    const float* __restrict__ bias,
    unsigned short* __restrict__ Cb, float* __restrict__ Cf, int ldc,
    int K, int nnt, size_t zstride) {
  __shared__ __align__(16) unsigned short As[4][8192];
  __shared__ __align__(16) unsigned short Bs[4][8192];
  int nwg = gridDim.x;
  int bid = blockIdx.x;
  int cpx = nwg >> 3;                       // nwg % 8 == 0 for all our grids
  int swz = (bid & 7) * cpx + (bid >> 3);   // XCD-aware bijective swizzle
  int mt = swz / nnt, nt = swz % nnt;
  int m0 = mt * 256, n0 = nt * 256;
  int tid = threadIdx.x, w = tid >> 6, l = tid & 63;
  int wm = (w >> 2) * 128, wn = (w & 3) * 64;
  int kb = blockIdx.z * K;

  // staging: granule G in {tid, 512+tid}; r = G>>2 (and +128), gp = G&3.
  // physical slot (r,gp) holds logical granule gp ^ ((r>>1)&3)  [involution]
  int sr = tid >> 2;
  int gsrc = (tid & 3) ^ ((sr >> 1) & 3);
  const unsigned short* Ag0 = A + (size_t)(m0 + sr) * lda + kb + gsrc * 8;
  const unsigned short* Ag1 = Ag0 + (size_t)128 * lda;
  const unsigned short* Bg0 = Bt + (size_t)(n0 + sr) * ldb + kb + gsrc * 8;
  const unsigned short* Bg1 = Bg0 + (size_t)128 * ldb;
  unsigned short* dA0 = &As[0][tid * 8];
  unsigned short* dA1 = &As[0][(512 + tid) * 8];
  unsigned short* dB0 = &Bs[0][tid * 8];
  unsigned short* dB1 = &Bs[0][(512 + tid) * 8];

  // fragment reads: logical row wm/wn + fr*16 + (l&15), logical granule l>>4
  int lswz = (l >> 1) & 3;                  // == ((l&15)>>1)&3
  int acol = ((l >> 4) ^ lswz) * 8;
  const unsigned short* Afr = &As[0][(wm + (l & 15)) * 32 + acol];
  const unsigned short* Bfr = &Bs[0][(wn + (l & 15)) * 32 + acol];

  f32x4 acc[8][4] = {};
  int nkt = K >> 5;

#define STAGE(t) do { int _k = (t) * 32; int _b = ((t) & 3) * 8192; \
    GLDS16(Ag0 + _k, dA0 + _b); GLDS16(Ag1 + _k, dA1 + _b); \
    GLDS16(Bg0 + _k, dB0 + _b); GLDS16(Bg1 + _k, dB1 + _b); } while (0)

  STAGE(0); STAGE(1); STAGE(2);
  for (int t = 0; t < nkt; ++t) {
    int rem = nkt - t;
    if (rem >= 3)      { asm volatile("s_waitcnt vmcnt(8)" ::: "memory"); }
    else if (rem == 2) { asm volatile("s_waitcnt vmcnt(4)" ::: "memory"); }
    else               { asm volatile("s_waitcnt vmcnt(0)" ::: "memory"); }
    __builtin_amdgcn_s_barrier();
    __builtin_amdgcn_sched_barrier(0);
    if (t + 3 < nkt) STAGE(t + 3);
    const unsigned short* ab = Afr + (t & 3) * 8192;
    const unsigned short* bb = Bfr + (t & 3) * 8192;
    s16x8 bf[4], af[4];
#pragma unroll
    for (int nr = 0; nr < 4; ++nr) bf[nr] = *(const s16x8*)(bb + nr * 512);
#pragma unroll
    for (int mr = 0; mr < 4; ++mr) af[mr] = *(const s16x8*)(ab + mr * 512);
    __builtin_amdgcn_s_setprio(1);
#pragma unroll
    for (int mr = 0; mr < 4; ++mr)
#pragma unroll
      for (int nr = 0; nr < 4; ++nr)
        acc[mr][nr] = MFMA(af[mr], bf[nr], acc[mr][nr]);
    __builtin_amdgcn_s_setprio(0);
#pragma unroll
    for (int mr = 0; mr < 4; ++mr) af[mr] = *(const s16x8*)(ab + (mr + 4) * 512);
    __builtin_amdgcn_s_setprio(1);
#pragma unroll
    for (int mr = 0; mr < 4; ++mr)
#pragma unroll
      for (int nr = 0; nr < 4; ++nr)
        acc[mr + 4][nr] = MFMA(af[mr], bf[nr], acc[mr + 4][nr]);
    __builtin_amdgcn_s_setprio(0);
  }
#undef STAGE

  float* Cfz = (MODE == 3) ? (Cf + zstride * blockIdx.z) : Cf;
#pragma unroll
  for (int mr = 0; mr < 8; ++mr) {
    int rb = m0 + wm + mr * 16 + (l >> 4) * 4;
#pragma unroll
    for (int nr = 0; nr < 4; ++nr) {
      int col = n0 + wn + nr * 16 + (l & 15);
      float bv = (MODE == 3) ? 0.f : bias[col];
#pragma unroll
      for (int j = 0; j < 4; ++j) {
        float v = acc[mr][nr][j] + bv;
        size_t off = (size_t)(rb + j) * ldc + col;
        if (MODE == 1) v = fmaxf(v, 0.f);
        if (MODE == 3) Cfz[off] = v;
        else Cb[off] = f2bf(v);
      }
    }
  }
}

// ---------------- FF2 split-K reduce + bias + bf16 residual + LN partials ----------------
__global__ __launch_bounds__(256) void k_ff2_reduce(
    float* __restrict__ acc,                   // [2][4096][1024]; out in slice 0
    const float* __restrict__ bias,            // [1024]
    const unsigned short* __restrict__ resid,  // h1b bf16 [4096][1024]
    float* __restrict__ partials) {
  __shared__ float red[8];
  int b = blockIdx.y;
  int row = b * 2048 + blockIdx.x;
  size_t base = (size_t)row * 1024;
  int c = threadIdx.x * 4;
  float4 v0 = *(const float4*)(acc + base + c);
  float4 v1 = *(const float4*)(acc + 4194304 + base + c);
  float4 bv = *(const float4*)(bias + c);
  u16x4 rv = *(const u16x4*)(resid + base + c);
  float4 o;
  o.x = v0.x + v1.x + bv.x + bf2f(rv.x);
  o.y = v0.y + v1.y + bv.y + bf2f(rv.y);
  o.z = v0.z + v1.z + bv.z + bf2f(rv.z);
  o.w = v0.w + v1.w + bv.w + bf2f(rv.w);
  *(float4*)(acc + base + c) = o;
  float bsum = o.x + o.y + o.z + o.w;
  float bsq = o.x * o.x + o.y * o.y + o.z * o.z + o.w * o.w;
  int wv = threadIdx.x >> 6, lv = threadIdx.x & 63;
#pragma unroll
  for (int mk = 1; mk < 64; mk <<= 1) { bsum += __shfl_xor(bsum, mk); bsq += __shfl_xor(bsq, mk); }
  if (lv == 0) { red[wv] = bsum; red[4 + wv] = bsq; }
  __syncthreads();
  if (threadIdx.x == 0) {
    float s = red[0] + red[1] + red[2] + red[3];
    float q = red[4] + red[5] + red[6] + red[7];
    partials[(b * 2048 + blockIdx.x) * 2] = s;
    partials[(b * 2048 + blockIdx.x) * 2 + 1] = q;
  }
}

// ---------------- V transpose per head: (s, d) -> (d, s), bf16 ----------------
__global__ __launch_bounds__(256) void k_transpose_v(const unsigned short* __restrict__ V, int ldv,
                                                     unsigned short* __restrict__ Vt, int S, int H) {
  __shared__ __align__(16) unsigned short t[64][72];
  int s0 = blockIdx.x * 64;
  int bh = blockIdx.y; int b = bh / H, h = bh % H;
  const unsigned short* src = V + (size_t)(b * S) * ldv + h * 64;
  unsigned short* dst = Vt + (size_t)bh * 64 * S;
  int tid = threadIdx.x;
#pragma unroll
  for (int i = 0; i < 2; ++i) {
    int idx = tid + i * 256;
    int s = idx >> 3, c = (idx & 7) * 8;
    s16x8 v = *(const s16x8*)(src + (size_t)(s0 + s) * ldv + c);
#pragma unroll
    for (int j = 0; j < 8; ++j) t[c + j][s] = (unsigned short)v[j];
  }
  __syncthreads();
#pragma unroll
  for (int i = 0; i < 2; ++i) {
    int idx = tid + i * 256;
    int d = idx >> 3, c = (idx & 7) * 8;
    *(s16x8*)(dst + (size_t)d * S + s0 + c) = *(const s16x8*)&t[d][c];
  }
}

// ---------------- causal flash attention + residual + LN partials ----------------
__global__ __launch_bounds__(256) void k_attn(
    const unsigned short* __restrict__ Qg, const unsigned short* __restrict__ Kg,
    const unsigned short* __restrict__ Vt, int ldqk,
    const float* __restrict__ x, float* __restrict__ hpre,
    float* __restrict__ partials, int S, int H) {
  __shared__ __align__(16) unsigned short Ks[2][64 * 64];
  __shared__ __align__(16) unsigned short Vs[2][64 * 64];
  __shared__ __align__(16) unsigned short Ps[4][16 * 64];
  __shared__ float red[8];
  int bh = blockIdx.y, b = bh / H, h = bh % H;
  int tid = threadIdx.x, w = tid >> 6, l = tid & 63;
  const int U = H * 64;
  const int nqt = S / 64;
  const unsigned short* Qb = Qg + (size_t)(b * S) * ldqk + h * 64;
  const unsigned short* Kb = Kg + (size_t)(b * S) * ldqk + h * 64;
  const unsigned short* Vb = Vt + (size_t)bh * 64 * S;
  const float* xb = x + (size_t)(b * S) * U + h * 64;
  float* hb = hpre + (size_t)(b * S) * U + h * 64;
  int sg_r[2], sg_c[2];
#pragma unroll
  for (int it = 0; it < 2; ++it) {
    int g = it * 256 + tid;
    sg_r[it] = g >> 3;
    sg_c[it] = ((g & 7) ^ ((g >> 3) & 7)) * 8;
  }
  unsigned short* Pw = &Ps[w][0];

  for (int pass = 0; pass < 2; ++pass) {
    int qt = (pass == 0) ? (int)blockIdx.x : (nqt - 1 - (int)blockIdx.x);
    int qrow = qt * 64 + w * 16 + (l & 15);
    s16x8 qf0 = *(const s16x8*)(Qb + (size_t)qrow * ldqk + (l >> 4) * 8);
    s16x8 qf1 = *(const s16x8*)(Qb + (size_t)qrow * ldqk + 32 + (l >> 4) * 8);
    f32x4 o[4] = {};
    float mrun[4] = {-1e30f, -1e30f, -1e30f, -1e30f};
    float lrun[4] = {0.f, 0.f, 0.f, 0.f};
    int qcd = qt * 64 + w * 16 + (l >> 4) * 4;

#pragma unroll
    for (int it = 0; it < 2; ++it) {
      GLDS16(Kb + (size_t)sg_r[it] * ldqk + sg_c[it], &Ks[0][(it * 256 + tid) * 8]);
      GLDS16(Vb + (size_t)sg_r[it] * S + sg_c[it], &Vs[0][(it * 256 + tid) * 8]);
    }

    for (int kt = 0; kt <= qt; ++kt) {
      int cur = kt & 1;
      __syncthreads();
      if (kt < qt) {
        int nb = cur ^ 1, kn = (kt + 1) * 64;
#pragma unroll
        for (int it = 0; it < 2; ++it) {
          GLDS16(Kb + (size_t)(kn + sg_r[it]) * ldqk + sg_c[it], &Ks[nb][(it * 256 + tid) * 8]);
          GLDS16(Vb + (size_t)sg_r[it] * S + kn + sg_c[it], &Vs[nb][(it * 256 + tid) * 8]);
        }
      }
      f32x4 sc[4];
      __builtin_amdgcn_s_setprio(1);
#pragma unroll
      for (int fn = 0; fn < 4; ++fn) {
        int row = fn * 16 + (l & 15);
        s16x8 kf0 = *(const s16x8*)&Ks[cur][row * 64 + ((((l >> 4)) ^ (row & 7)) * 8)];
        s16x8 kf1 = *(const s16x8*)&Ks[cur][row * 64 + (((4 + (l >> 4)) ^ (row & 7)) * 8)];
        f32x4 z = {};
        z = MFMA(qf0, kf0, z);
        z = MFMA(qf1, kf1, z);
        sc[fn] = z;
      }
      __builtin_amdgcn_s_setprio(0);
      if (kt == qt) {
#pragma unroll
        for (int fn = 0; fn < 4; ++fn) {
          int key = kt * 64 + fn * 16 + (l & 15);
#pragma unroll
          for (int j = 0; j < 4; ++j)
            sc[fn][j] = (key > qcd + j) ? -1e30f : sc[fn][j];
        }
      }
#pragma unroll
      for (int j = 0; j < 4; ++j) {
        float mx = fmaxf(fmaxf(sc[0][j], sc[1][j]), fmaxf(sc[2][j], sc[3][j]));
#pragma unroll
        for (int mk = 1; mk < 16; mk <<= 1) mx = fmaxf(mx, __shfl_xor(mx, mk));
        float mnew = fmaxf(mrun[j], mx);
        float alpha = __expf(mrun[j] - mnew);
        float rs = 0.f;
#pragma unroll
        for (int fn = 0; fn < 4; ++fn) { float p = __expf(sc[fn][j] - mnew); sc[fn][j] = p; rs += p; }
#pragma unroll
        for (int mk = 1; mk < 16; mk <<= 1) rs += __shfl_xor(rs, mk);
        mrun[j] = mnew;
        lrun[j] = lrun[j] * alpha + rs;
#pragma unroll
        for (int fn = 0; fn < 4; ++fn) o[fn][j] *= alpha;
      }
#pragma unroll
      for (int fn = 0; fn < 4; ++fn)
#pragma unroll
        for (int j = 0; j < 4; ++j) {
          int row = (l >> 4) * 4 + j;
          int col = fn * 16 + (l & 15);
          Pw[row * 64 + (col ^ ((row & 7) * 8))] = f2bf(sc[fn][j]);
        }
      __builtin_amdgcn_s_setprio(1);
#pragma unroll
      for (int kk = 0; kk < 2; ++kk) {
        int prow = l & 15;
        s16x8 pa = *(const s16x8*)&Pw[prow * 64 + (((kk * 4 + (l >> 4)) ^ (prow & 7)) * 8)];
#pragma unroll
        for (int fd = 0; fd < 4; ++fd) {
          int vrow = fd * 16 + (l & 15);
          s16x8 vf = *(const s16x8*)&Vs[cur][vrow * 64 + (((kk * 4 + (l >> 4)) ^ (vrow & 7)) * 8)];
          o[fd] = MFMA(pa, vf, o[fd]);
        }
      }
      __builtin_amdgcn_s_setprio(0);
    }
    float bsum = 0.f, bsq = 0.f;
#pragma unroll
    for (int fd = 0; fd < 4; ++fd) {
      int col = fd * 16 + (l & 15);
#pragma unroll
      for (int j = 0; j < 4; ++j) {
        int row = qcd + j;
        float v = o[fd][j] / lrun[j] + xb[(size_t)row * U + col];
        hb[(size_t)row * U + col] = v;
        bsum += v; bsq += v * v;
      }
    }
#pragma unroll
    for (int mk = 1; mk < 64; mk <<= 1) { bsum += __shfl_xor(bsum, mk); bsq += __shfl_xor(bsq, mk); }
    if (l == 0) { red[w] = bsum; red[4 + w] = bsq; }
    __syncthreads();
    if (tid == 0) {
      float s2 = red[0] + red[1] + red[2] + red[3];
      float q2 = red[4] + red[5] + red[6] + red[7];
      int pi = b * (H * nqt) + h * nqt + qt;
      partials[pi * 2] = s2; partials[pi * 2 + 1] = q2;
    }
    __syncthreads();
  }
}

// ---------------- LN over (S,U) per batch ----------------
__global__ __launch_bounds__(256) void k_ln_stats(const float* __restrict__ partials, int nper,
                                                  float* __restrict__ stats, float invN) {
  int b = blockIdx.x, tid = threadIdx.x;
  float s = 0.f, q = 0.f;
  for (int i = tid; i < nper; i += 256) { s += partials[(b * nper + i) * 2]; q += partials[(b * nper + i) * 2 + 1]; }
#pragma unroll
  for (int mk = 1; mk < 64; mk <<= 1) { s += __shfl_xor(s, mk); q += __shfl_xor(q, mk); }
  __shared__ float red[8];
  int w = tid >> 6, l = tid & 63;
  if (l == 0) { red[w] = s; red[4 + w] = q; }
  __syncthreads();
  if (tid == 0) {
    s = red[0] + red[1] + red[2] + red[3];
    q = red[4] + red[5] + red[6] + red[7];
    float m = s * invN, var = q * invN - m * m;
    stats[b * 2] = m; stats[b * 2 + 1] = rsqrtf(var + 1e-5f);
  }
}

__global__ __launch_bounds__(256) void k_ln_apply(
    const float* __restrict__ src, const float* __restrict__ stats,
    const float* __restrict__ g, const float* __restrict__ bt,
    float* __restrict__ outf, unsigned short* __restrict__ outb, int SU) {
  int b = blockIdx.y;
  int idx = (blockIdx.x * 256 + threadIdx.x) * 4;
  float m = stats[b * 2], r = stats[b * 2 + 1];
  float4 v = *(const float4*)(src + (size_t)b * SU + idx);
  float4 gg = *(const float4*)(g + idx);
  float4 bb = *(const float4*)(bt + idx);
  float4 o;
  o.x = (v.x - m) * r * gg.x + bb.x;
  o.y = (v.y - m) * r * gg.y + bb.y;
  o.z = (v.z - m) * r * gg.z + bb.z;
  o.w = (v.w - m) * r * gg.w + bb.w;
  if (outf) *(float4*)(outf + (size_t)b * SU + idx) = o;
  if (outb) {
    u16x4 ob; ob.x = f2bf(o.x); ob.y = f2bf(o.y); ob.z = f2bf(o.z); ob.w = f2bf(o.w);
    *(u16x4*)(outb + (size_t)b * SU + idx) = ob;
  }
}

extern "C" void kernel_launch(void* const* d_in, const int* in_sizes, int n_in,
                              void* d_out, int out_size, void* d_ws, size_t ws_size,
                              hipStream_t stream) {
  (void)in_sizes; (void)n_in; (void)out_size; (void)ws_size;
  const int S = 2048, H = 16;
  const float* x   = (const float*)d_in[0];
  const float* wq  = (const float*)d_in[1];
  const float* bq  = (const float*)d_in[2];
  const float* wk  = (const float*)d_in[3];
  const float* bk  = (const float*)d_in[4];
  const float* wv  = (const float*)d_in[5];
  const float* bv  = (const float*)d_in[6];
  const float* wf1 = (const float*)d_in[7];
  const float* bf1 = (const float*)d_in[8];
  const float* wf2 = (const float*)d_in[9];
  const float* bf2 = (const float*)d_in[10];
  const float* lng = (const float*)d_in[11];
  const float* lnb = (const float*)d_in[12];
  const float* ffg = (const float*)d_in[13];
  const float* ffb = (const float*)d_in[14];

  char* ws = (char*)d_ws;
  unsigned short* wqkvT = (unsigned short*)(ws);              // 3072x1024 bf16 (dead after QKV)
  unsigned short* wf1T  = (unsigned short*)(ws + 6291456);    // 4096x1024 bf16
  unsigned short* wf2T  = (unsigned short*)(ws + 14680064);   // 1024x4096 bf16
  unsigned short* xb    = (unsigned short*)(ws + 23068672);   // 4096x1024 bf16 (dead after QKV)
  unsigned short* qkv   = (unsigned short*)(ws + 31457280);   // 4096x3072 bf16 (dead after attn)
  unsigned short* vt    = (unsigned short*)(ws + 56623104);   // 32x64x2048 bf16 (dead after attn)
  unsigned short* h1b   = (unsigned short*)(ws + 65011712);   // 4096x1024 bf16 (LN1 out)
  float* hpre           = (float*)(ws + 73400320);            // 4096x1024 f32 + adjacent FF2 slice1
  float* ff2p1          = (float*)(ws + 90177536);            // 4096x1024 f32 (FF2 slice 1)
  unsigned short* f1b   = (unsigned short*)(ws + 23068672);   // 4096x4096 bf16 (over xb+qkv)
  float* biasqkv        = (float*)(ws + 106954752);           // 3072 f32
  float* part_attn      = (float*)(ws + 106967040);           // 2*512*2 f32
  float* stats1         = (float*)(ws + 106977280);           // 2*2 f32
  float* ffpart2        = (float*)(ws);                       // 2*2048*2 f32 (over wqkvT, dead)
  float* stats2         = (float*)(ws + 65536);               // 2*2 f32 (over wqkvT, dead)

  // 1. conversions / transposes (Q path pre-scaled by 1/sqrt(dh)=0.125)
  k_f32_to_bf16<<<4096, 256, 0, stream>>>(x, xb, 4096 * 1024 / 4);
  k_transpose_w<<<dim3(16, 16), 256, 0, stream>>>(wq, wqkvT, 1024, 1024, 0.125f);
  k_transpose_w<<<dim3(16, 16), 256, 0, stream>>>(wk, wqkvT + 1024 * 1024, 1024, 1024, 1.0f);
  k_transpose_w<<<dim3(16, 16), 256, 0, stream>>>(wv, wqkvT + 2048 * 1024, 1024, 1024, 1.0f);
  k_transpose_w<<<dim3(16, 64), 256, 0, stream>>>(wf1, wf1T, 1024, 4096, 1.0f);
  k_transpose_w<<<dim3(64, 16), 256, 0, stream>>>(wf2, wf2T, 4096, 1024, 1.0f);
  k_concat3<<<12, 256, 0, stream>>>(bq, bk, bv, biasqkv, 1024, 0.125f);

  // 2. fused QKV projection: (4096x1024) @ (1024x3072), 16x12 = 192 blocks
  k_gemm8<0><<<dim3(192, 1, 1), 512, 0, stream>>>(xb, 1024, wqkvT, 1024, biasqkv,
      qkv, nullptr, 3072, 1024, 12, 0);

  // 3. V transpose per head
  k_transpose_v<<<dim3(32, 32), 256, 0, stream>>>(qkv + 2048, 3072, vt, S, H);

  // 4. causal flash attention + x residual + LN1 partials (paired q-tiles)
  k_attn<<<dim3(16, 32), 256, 0, stream>>>(qkv, qkv + 1024, vt, 3072, x, hpre, part_attn, S, H);

  // 5. LN1 -> bf16 only
  k_ln_stats<<<2, 256, 0, stream>>>(part_attn, 512, stats1, 1.f / (2048.f * 1024.f));
  k_ln_apply<<<dim3(2048, 2), 256, 0, stream>>>(hpre, stats1, lng, lnb, nullptr, h1b, S * 1024);

  // 6. FF1: (4096x1024) @ (1024x4096), ReLU, 16x16 = 256 blocks
  k_gemm8<1><<<dim3(256, 1, 1), 512, 0, stream>>>(h1b, 1024, wf1T, 1024, bf1,
      f1b, nullptr, 4096, 1024, 16, 0);

  // 7. FF2: (4096x4096) @ (4096x1024), split-K=2, 16x4x2 = 128 blocks -> f32 partials
  k_gemm8<3><<<dim3(64, 1, 2), 512, 0, stream>>>(f1b, 4096, wf2T, 4096, nullptr,
      nullptr, hpre, 1024, 2048, 4, 4194304);

  // 8. reduce slices + bias + bf16 residual -> hpre, LN2 partials
  k_ff2_reduce<<<dim3(2048, 2), 256, 0, stream>>>(hpre, bf2, h1b, ffpart2);

  // 9. LN2 -> d_out (fp32)
  k_ln_stats<<<2, 256, 0, stream>>>(ffpart2, 2048, stats2, 1.f / (2048.f * 1024.f));
  k_ln_apply<<<dim3(2048, 2), 256, 0, stream>>>(hpre, stats2, ffg, ffb, (float*)d_out, nullptr, S * 1024);
}

// Round 4
// 257.749 us; speedup vs baseline: 1.5446x; 1.1928x over previous
//
#include <hip/hip_runtime.h>

typedef short s16x8 __attribute__((ext_vector_type(8)));
typedef float f32x4 __attribute__((ext_vector_type(4)));
typedef unsigned short u16x4 __attribute__((ext_vector_type(4)));

#define DEV static __device__ __forceinline__

DEV unsigned short f2bf(float f) {
  union { float f; unsigned u; } v; v.f = f;
  unsigned r = v.u + 0x7FFFu + ((v.u >> 16) & 1u);
  return (unsigned short)(r >> 16);
}
DEV float bf2f(unsigned short u) {
  union { unsigned u; float f; } v; v.u = (unsigned)u << 16; return v.f;
}

#define GLDS16(src, dst) \
  __builtin_amdgcn_global_load_lds((const __attribute__((address_space(1))) void*)(src), \
                                   (__attribute__((address_space(3))) void*)(dst), 16, 0, 0)

#define MFMA(a, b, c) __builtin_amdgcn_mfma_f32_16x16x32_bf16((a), (b), (c), 0, 0, 0)

// ---------------- elementwise fp32 -> bf16 ----------------
__global__ __launch_bounds__(256) void k_f32_to_bf16(const float* __restrict__ in,
                                                     unsigned short* __restrict__ out, int n4) {
  int i = blockIdx.x * 256 + threadIdx.x;
  if (i >= n4) return;
  float4 v = ((const float4*)in)[i];
  u16x4 o; o.x = f2bf(v.x); o.y = f2bf(v.y); o.z = f2bf(v.z); o.w = f2bf(v.w);
  ((u16x4*)out)[i] = o;
}

// ---------------- weight transpose+convert: (K,N) f32 -> (N,K) bf16, with scale ----------------
__global__ __launch_bounds__(256) void k_transpose_w(const float* __restrict__ W,
                                                     unsigned short* __restrict__ Wt,
                                                     int K, int N, float scale) {
  __shared__ float t[64][65];
  int k0 = blockIdx.x * 64, n0 = blockIdx.y * 64;
  int tid = threadIdx.x;
#pragma unroll
  for (int i = 0; i < 16; ++i) {
    int idx = tid + i * 256; int r = idx >> 6, c = idx & 63;
    t[r][c] = W[(size_t)(k0 + r) * N + (n0 + c)];
  }
  __syncthreads();
#pragma unroll
  for (int i = 0; i < 16; ++i) {
    int idx = tid + i * 256; int r = idx >> 6, c = idx & 63;
    Wt[(size_t)(n0 + r) * K + (k0 + c)] = f2bf(t[c][r] * scale);
  }
}

// ---------------- concat 3 bias vectors (a gets scale) ----------------
__global__ void k_concat3(const float* __restrict__ a, const float* __restrict__ b,
                          const float* __restrict__ c, float* __restrict__ out, int n, float sa) {
  int i = blockIdx.x * 256 + threadIdx.x;
  if (i >= 3 * n) return;
  int j = (i < n) ? i : (i < 2 * n ? i - n : i - 2 * n);
  out[i] = (i < n) ? a[j] * sa : (i < 2 * n ? b[j] : c[j]);
}

// ---------------- BMx256 pipelined GEMM: C = A(MxK) * Bt(NxK)^T ----------------
// BK=32, 4-deep LDS ring, 8 waves, counted vmcnt (never 0 in main loop),
// XOR-swizzled LDS (both-sides), setprio, XCD block swizzle.
// MODE 0: bias -> bf16. MODE 1: bias+relu -> bf16. MODE 3: raw f32 partial
// (no bias) at Cf + blockIdx.z*zstride, K is per-slice length.
template <int MODE, int BM>
__global__ __launch_bounds__(512, 2) void k_gemm8(
    const unsigned short* __restrict__ A, int lda,
    const unsigned short* __restrict__ Bt, int ldb,
    const float* __restrict__ bias,
    unsigned short* __restrict__ Cb, float* __restrict__ Cf, int ldc,
    int K, int nnt, size_t zstride) {
  constexpr int MR = BM / 32;              // acc row-blocks per wave
  constexpr int ASLOT = BM * 32;           // A ring-slot elements
  __shared__ __align__(16) unsigned short As[4 * ASLOT];
  __shared__ __align__(16) unsigned short Bs[4 * 8192];
  int nwg = gridDim.x;
  int bid = blockIdx.x;
  int cpx = nwg >> 3;                       // nwg % 8 == 0 for all our grids
  int swz = (bid & 7) * cpx + (bid >> 3);   // XCD-aware bijective swizzle
  int mt = swz / nnt, nt = swz % nnt;
  int m0 = mt * BM, n0 = nt * 256;
  int tid = threadIdx.x, w = tid >> 6, l = tid & 63;
  int wm = (w >> 2) * (BM / 2), wn = (w & 3) * 64;
  int kb = blockIdx.z * K;

  // staging: row sr = tid>>2 (and +128 for BM=256), granule gp = tid&3.
  // physical slot (r,gp) holds logical granule gp ^ ((r>>1)&3)  [involution]
  int sr = tid >> 2;
  int gsrc = (tid & 3) ^ ((sr >> 1) & 3);
  const unsigned short* Ag0 = A + (size_t)(m0 + sr) * lda + kb + gsrc * 8;
  const unsigned short* Ag1 = Ag0 + (size_t)128 * lda;
  const unsigned short* Bg0 = Bt + (size_t)(n0 + sr) * ldb + kb + gsrc * 8;
  const unsigned short* Bg1 = Bg0 + (size_t)128 * ldb;
  unsigned short* dA0 = &As[tid * 8];
  unsigned short* dA1 = dA0 + 4096;
  unsigned short* dB0 = &Bs[tid * 8];
  unsigned short* dB1 = dB0 + 4096;

  // fragment reads: logical row wm/wn + fr*16 + (l&15), logical granule l>>4
  int lswz = (l >> 1) & 3;
  int acol = ((l >> 4) ^ lswz) * 8;
  const unsigned short* Afr = &As[(wm + (l & 15)) * 32 + acol];
  const unsigned short* Bfr = &Bs[(wn + (l & 15)) * 32 + acol];

  f32x4 acc[MR][4] = {};
  int nkt = K >> 5;

#define STAGE(t) do { int _k = (t) * 32; \
    GLDS16(Ag0 + _k, dA0 + ((t) & 3) * ASLOT); \
    if constexpr (BM == 256) GLDS16(Ag1 + _k, dA1 + ((t) & 3) * ASLOT); \
    GLDS16(Bg0 + _k, dB0 + ((t) & 3) * 8192); \
    GLDS16(Bg1 + _k, dB1 + ((t) & 3) * 8192); } while (0)

  STAGE(0); STAGE(1); STAGE(2);
  for (int t = 0; t < nkt; ++t) {
    int rem = nkt - t;
    if (rem >= 3) {
      if constexpr (BM == 256) asm volatile("s_waitcnt vmcnt(8)" ::: "memory");
      else                     asm volatile("s_waitcnt vmcnt(6)" ::: "memory");
    } else if (rem == 2) {
      if constexpr (BM == 256) asm volatile("s_waitcnt vmcnt(4)" ::: "memory");
      else                     asm volatile("s_waitcnt vmcnt(3)" ::: "memory");
    } else {
      asm volatile("s_waitcnt vmcnt(0)" ::: "memory");
    }
    __builtin_amdgcn_s_barrier();
    __builtin_amdgcn_sched_barrier(0);
    if (t + 3 < nkt) STAGE(t + 3);
    const unsigned short* ab = Afr + (t & 3) * ASLOT;
    const unsigned short* bb = Bfr + (t & 3) * 8192;
    s16x8 bf[4], af[4];
#pragma unroll
    for (int nr = 0; nr < 4; ++nr) bf[nr] = *(const s16x8*)(bb + nr * 512);
#pragma unroll
    for (int mr = 0; mr < 4; ++mr) af[mr] = *(const s16x8*)(ab + mr * 512);
    __builtin_amdgcn_s_setprio(1);
#pragma unroll
    for (int mr = 0; mr < 4; ++mr)
#pragma unroll
      for (int nr = 0; nr < 4; ++nr)
        acc[mr][nr] = MFMA(af[mr], bf[nr], acc[mr][nr]);
    __builtin_amdgcn_s_setprio(0);
    if constexpr (MR == 8) {
#pragma unroll
      for (int mr = 0; mr < 4; ++mr) af[mr] = *(const s16x8*)(ab + (mr + 4) * 512);
      __builtin_amdgcn_s_setprio(1);
#pragma unroll
      for (int mr = 0; mr < 4; ++mr)
#pragma unroll
        for (int nr = 0; nr < 4; ++nr)
          acc[mr + 4][nr] = MFMA(af[mr], bf[nr], acc[mr + 4][nr]);
      __builtin_amdgcn_s_setprio(0);
    }
  }
#undef STAGE

  float* Cfz = (MODE == 3) ? (Cf + zstride * blockIdx.z) : Cf;
#pragma unroll
  for (int mr = 0; mr < MR; ++mr) {
    int rb = m0 + wm + mr * 16 + (l >> 4) * 4;
#pragma unroll
    for (int nr = 0; nr < 4; ++nr) {
      int col = n0 + wn + nr * 16 + (l & 15);
      float bv = (MODE == 3) ? 0.f : bias[col];
#pragma unroll
      for (int j = 0; j < 4; ++j) {
        float v = acc[mr][nr][j] + bv;
        size_t off = (size_t)(rb + j) * ldc + col;
        if (MODE == 1) v = fmaxf(v, 0.f);
        if (MODE == 3) Cfz[off] = v;
        else Cb[off] = f2bf(v);
      }
    }
  }
}

// ---------------- FF2 split-K reduce + bias + bf16 residual + LN partials ----------------
__global__ __launch_bounds__(256) void k_ff2_reduce(
    float* __restrict__ acc,                   // [2][4096][1024]; out in slice 0
    const float* __restrict__ bias,            // [1024]
    const unsigned short* __restrict__ resid,  // h1b bf16 [4096][1024]
    float* __restrict__ partials) {
  __shared__ float red[8];
  int b = blockIdx.y;
  int row = b * 2048 + blockIdx.x;
  size_t base = (size_t)row * 1024;
  int c = threadIdx.x * 4;
  float4 v0 = *(const float4*)(acc + base + c);
  float4 v1 = *(const float4*)(acc + 4194304 + base + c);
  float4 bv = *(const float4*)(bias + c);
  u16x4 rv = *(const u16x4*)(resid + base + c);
  float4 o;
  o.x = v0.x + v1.x + bv.x + bf2f(rv.x);
  o.y = v0.y + v1.y + bv.y + bf2f(rv.y);
  o.z = v0.z + v1.z + bv.z + bf2f(rv.z);
  o.w = v0.w + v1.w + bv.w + bf2f(rv.w);
  *(float4*)(acc + base + c) = o;
  float bsum = o.x + o.y + o.z + o.w;
  float bsq = o.x * o.x + o.y * o.y + o.z * o.z + o.w * o.w;
  int wv = threadIdx.x >> 6, lv = threadIdx.x & 63;
#pragma unroll
  for (int mk = 1; mk < 64; mk <<= 1) { bsum += __shfl_xor(bsum, mk); bsq += __shfl_xor(bsq, mk); }
  if (lv == 0) { red[wv] = bsum; red[4 + wv] = bsq; }
  __syncthreads();
  if (threadIdx.x == 0) {
    float s = red[0] + red[1] + red[2] + red[3];
    float q = red[4] + red[5] + red[6] + red[7];
    partials[(b * 2048 + blockIdx.x) * 2] = s;
    partials[(b * 2048 + blockIdx.x) * 2 + 1] = q;
  }
}

// ---------------- V transpose per head: (s, d) -> (d, s), bf16 ----------------
__global__ __launch_bounds__(256) void k_transpose_v(const unsigned short* __restrict__ V, int ldv,
                                                     unsigned short* __restrict__ Vt, int S, int H) {
  __shared__ __align__(16) unsigned short t[64][72];
  int s0 = blockIdx.x * 64;
  int bh = blockIdx.y; int b = bh / H, h = bh % H;
  const unsigned short* src = V + (size_t)(b * S) * ldv + h * 64;
  unsigned short* dst = Vt + (size_t)bh * 64 * S;
  int tid = threadIdx.x;
#pragma unroll
  for (int i = 0; i < 2; ++i) {
    int idx = tid + i * 256;
    int s = idx >> 3, c = (idx & 7) * 8;
    s16x8 v = *(const s16x8*)(src + (size_t)(s0 + s) * ldv + c);
#pragma unroll
    for (int j = 0; j < 8; ++j) t[c + j][s] = (unsigned short)v[j];
  }
  __syncthreads();
#pragma unroll
  for (int i = 0; i < 2; ++i) {
    int idx = tid + i * 256;
    int d = idx >> 3, c = (idx & 7) * 8;
    *(s16x8*)(dst + (size_t)d * S + s0 + c) = *(const s16x8*)&t[d][c];
  }
}

// ---------------- causal flash attention + residual + LN partials ----------------
// Swapped QK^T (mfma(K,Q)): each lane owns one q-row's 16 scores -> in-reg
// softmax, 2 shfls per reduce. Defer-max (THR=8). Packed ds_write_b64 P.
// grid (bh=32, qt=32): bh pins K/V to one XCD L2; heavy q-tiles first.
__global__ __launch_bounds__(256) void k_attn(
    const unsigned short* __restrict__ Qg, const unsigned short* __restrict__ Kg,
    const unsigned short* __restrict__ Vt, int ldqk,
    const float* __restrict__ x, float* __restrict__ hpre,
    float* __restrict__ partials, int S, int H) {
  __shared__ __align__(16) unsigned short Ks[2][64 * 64];
  __shared__ __align__(16) unsigned short Vs[2][64 * 64];
  __shared__ __align__(16) unsigned short Ps[4][16 * 64];
  __shared__ float red[8];
  int bh = blockIdx.x, b = bh >> 4, h = bh & 15;
  const int nqt = S / 64;
  int qt = nqt - 1 - (int)blockIdx.y;   // heavy tiles dispatched first
  int tid = threadIdx.x, w = tid >> 6, l = tid & 63;
  const int U = H * 64;
  const unsigned short* Qb = Qg + (size_t)(b * S) * ldqk + h * 64;
  const unsigned short* Kb = Kg + (size_t)(b * S) * ldqk + h * 64;
  const unsigned short* Vb = Vt + (size_t)bh * 64 * S;
  const float* xb = x + (size_t)(b * S) * U + h * 64;
  float* hb = hpre + (size_t)(b * S) * U + h * 64;
  int sg_r[2], sg_c[2];
#pragma unroll
  for (int it = 0; it < 2; ++it) {
    int g = it * 256 + tid;
    sg_r[it] = g >> 3;
    sg_c[it] = ((g & 7) ^ ((g >> 3) & 7)) * 8;
  }
  unsigned short* Pw = &Ps[w][0];
  int qloc = l & 15;            // this lane's q-row (softmax owner layout)
  int kloc = (l >> 4) * 4;      // this lane's key sub-block base

  int qrow = qt * 64 + w * 16 + qloc;
  s16x8 qf0 = *(const s16x8*)(Qb + (size_t)qrow * ldqk + (l >> 4) * 8);
  s16x8 qf1 = *(const s16x8*)(Qb + (size_t)qrow * ldqk + 32 + (l >> 4) * 8);
  f32x4 o[4] = {};
  float m = -1e30f, lsum = 0.f;

#pragma unroll
  for (int it = 0; it < 2; ++it) {
    GLDS16(Kb + (size_t)sg_r[it] * ldqk + sg_c[it], &Ks[0][(it * 256 + tid) * 8]);
    GLDS16(Vb + (size_t)sg_r[it] * S + sg_c[it], &Vs[0][(it * 256 + tid) * 8]);
  }

  for (int kt = 0; kt <= qt; ++kt) {
    int cur = kt & 1;
    __syncthreads();
    if (kt < qt) {
      int nb = cur ^ 1, kn = (kt + 1) * 64;
#pragma unroll
      for (int it = 0; it < 2; ++it) {
        GLDS16(Kb + (size_t)(kn + sg_r[it]) * ldqk + sg_c[it], &Ks[nb][(it * 256 + tid) * 8]);
        GLDS16(Vb + (size_t)sg_r[it] * S + kn + sg_c[it], &Vs[nb][(it * 256 + tid) * 8]);
      }
    }
    // ---- QK^T swapped: sc[fn][j] = S[key = fn*16+kloc+j][q = qloc] ----
    f32x4 sc[4];
    __builtin_amdgcn_s_setprio(1);
#pragma unroll
    for (int fn = 0; fn < 4; ++fn) {
      int row = fn * 16 + (l & 15);
      s16x8 kf0 = *(const s16x8*)&Ks[cur][row * 64 + ((((l >> 4)) ^ (row & 7)) * 8)];
      s16x8 kf1 = *(const s16x8*)&Ks[cur][row * 64 + (((4 + (l >> 4)) ^ (row & 7)) * 8)];
      f32x4 z = {};
      z = MFMA(kf0, qf0, z);
      z = MFMA(kf1, qf1, z);
      sc[fn] = z;
    }
    __builtin_amdgcn_s_setprio(0);
    if (kt == qt) {
      int qsel = w * 16 + qloc;
#pragma unroll
      for (int fn = 0; fn < 4; ++fn)
#pragma unroll
        for (int j = 0; j < 4; ++j)
          if (fn * 16 + kloc + j > qsel) sc[fn][j] = -1e30f;
    }
    // ---- in-register row max (one q per lane) ----
    float mx = sc[0][0];
#pragma unroll
    for (int fn = 0; fn < 4; ++fn)
#pragma unroll
      for (int j = 0; j < 4; ++j) mx = fmaxf(mx, sc[fn][j]);
    mx = fmaxf(mx, __shfl_xor(mx, 16));
    mx = fmaxf(mx, __shfl_xor(mx, 32));
    // ---- defer-max: rescale only if max grew by > 8 ----
    if (__ballot(mx > m + 8.f)) {
      float mnew = fmaxf(m, mx);
      float alpha = __expf(m - mnew);
      m = mnew;
      lsum *= alpha;
#pragma unroll
      for (int j = 0; j < 4; ++j) {
        float aj = __shfl(alpha, (l & 48) | (kloc + j));
#pragma unroll
        for (int fd = 0; fd < 4; ++fd) o[fd][j] *= aj;
      }
    }
    // ---- p = exp(s - m), row sum, packed P write ----
    float rs = 0.f;
#pragma unroll
    for (int fn = 0; fn < 4; ++fn) {
      u16x4 pk;
#pragma unroll
      for (int j = 0; j < 4; ++j) {
        float p = __expf(sc[fn][j] - m);
        rs += p;
        ((unsigned short*)&pk)[j] = f2bf(p);
      }
      int kb2 = fn * 16 + kloc;
      int el = qloc * 64 + (((kb2 >> 3) ^ (qloc & 7)) * 8) + (kb2 & 7);
      *(u16x4*)&Pw[el] = pk;
    }
    rs += __shfl_xor(rs, 16);
    rs += __shfl_xor(rs, 32);
    lsum += rs;
    // ---- PV: O[q][d] += P[q][k] V[k][d] ----
    __builtin_amdgcn_s_setprio(1);
#pragma unroll
    for (int kk = 0; kk < 2; ++kk) {
      int prow = l & 15;
      s16x8 pa = *(const s16x8*)&Pw[prow * 64 + (((kk * 4 + (l >> 4)) ^ (prow & 7)) * 8)];
#pragma unroll
      for (int fd = 0; fd < 4; ++fd) {
        int vrow = fd * 16 + (l & 15);
        s16x8 vf = *(const s16x8*)&Vs[cur][vrow * 64 + (((kk * 4 + (l >> 4)) ^ (vrow & 7)) * 8)];
        o[fd] = MFMA(pa, vf, o[fd]);
      }
    }
    __builtin_amdgcn_s_setprio(0);
  }
  // ---- epilogue: O/l + x residual, write hpre, LN partial sums ----
  float bsum = 0.f, bsq = 0.f;
#pragma unroll
  for (int j = 0; j < 4; ++j) {
    float lr = __shfl(lsum, (l & 48) | (kloc + j));
    float inv = 1.f / lr;
    int row = qt * 64 + w * 16 + kloc + j;
#pragma unroll
    for (int fd = 0; fd < 4; ++fd) {
      int col = fd * 16 + (l & 15);
      float v = o[fd][j] * inv + xb[(size_t)row * U + col];
      hb[(size_t)row * U + col] = v;
      bsum += v; bsq += v * v;
    }
  }
#pragma unroll
  for (int mk = 1; mk < 64; mk <<= 1) { bsum += __shfl_xor(bsum, mk); bsq += __shfl_xor(bsq, mk); }
  if (l == 0) { red[w] = bsum; red[4 + w] = bsq; }
  __syncthreads();
  if (tid == 0) {
    float s2 = red[0] + red[1] + red[2] + red[3];
    float q2 = red[4] + red[5] + red[6] + red[7];
    int pi = b * (H * nqt) + h * nqt + qt;
    partials[pi * 2] = s2; partials[pi * 2 + 1] = q2;
  }
}

// ---------------- LN over (S,U) per batch ----------------
__global__ __launch_bounds__(256) void k_ln_stats(const float* __restrict__ partials, int nper,
                                                  float* __restrict__ stats, float invN) {
  int b = blockIdx.x, tid = threadIdx.x;
  float s = 0.f, q = 0.f;
  for (int i = tid; i < nper; i += 256) { s += partials[(b * nper + i) * 2]; q += partials[(b * nper + i) * 2 + 1]; }
#pragma unroll
  for (int mk = 1; mk < 64; mk <<= 1) { s += __shfl_xor(s, mk); q += __shfl_xor(q, mk); }
  __shared__ float red[8];
  int w = tid >> 6, l = tid & 63;
  if (l == 0) { red[w] = s; red[4 + w] = q; }
  __syncthreads();
  if (tid == 0) {
    s = red[0] + red[1] + red[2] + red[3];
    q = red[4] + red[5] + red[6] + red[7];
    float m = s * invN, var = q * invN - m * m;
    stats[b * 2] = m; stats[b * 2 + 1] = rsqrtf(var + 1e-5f);
  }
}

__global__ __launch_bounds__(256) void k_ln_apply(
    const float* __restrict__ src, const float* __restrict__ stats,
    const float* __restrict__ g, const float* __restrict__ bt,
    float* __restrict__ outf, unsigned short* __restrict__ outb, int SU) {
  int b = blockIdx.y;
  int idx = (blockIdx.x * 256 + threadIdx.x) * 4;
  float m = stats[b * 2], r = stats[b * 2 + 1];
  float4 v = *(const float4*)(src + (size_t)b * SU + idx);
  float4 gg = *(const float4*)(g + idx);
  float4 bb = *(const float4*)(bt + idx);
  float4 o;
  o.x = (v.x - m) * r * gg.x + bb.x;
  o.y = (v.y - m) * r * gg.y + bb.y;
  o.z = (v.z - m) * r * gg.z + bb.z;
  o.w = (v.w - m) * r * gg.w + bb.w;
  if (outf) *(float4*)(outf + (size_t)b * SU + idx) = o;
  if (outb) {
    u16x4 ob; ob.x = f2bf(o.x); ob.y = f2bf(o.y); ob.z = f2bf(o.z); ob.w = f2bf(o.w);
    *(u16x4*)(outb + (size_t)b * SU + idx) = ob;
  }
}

extern "C" void kernel_launch(void* const* d_in, const int* in_sizes, int n_in,
                              void* d_out, int out_size, void* d_ws, size_t ws_size,
                              hipStream_t stream) {
  (void)in_sizes; (void)n_in; (void)out_size; (void)ws_size;
  const int S = 2048, H = 16;
  const float* x   = (const float*)d_in[0];
  const float* wq  = (const float*)d_in[1];
  const float* bq  = (const float*)d_in[2];
  const float* wk  = (const float*)d_in[3];
  const float* bk  = (const float*)d_in[4];
  const float* wv  = (const float*)d_in[5];
  const float* bv  = (const float*)d_in[6];
  const float* wf1 = (const float*)d_in[7];
  const float* bf1 = (const float*)d_in[8];
  const float* wf2 = (const float*)d_in[9];
  const float* bf2 = (const float*)d_in[10];
  const float* lng = (const float*)d_in[11];
  const float* lnb = (const float*)d_in[12];
  const float* ffg = (const float*)d_in[13];
  const float* ffb = (const float*)d_in[14];

  char* ws = (char*)d_ws;
  unsigned short* wqkvT = (unsigned short*)(ws);              // 3072x1024 bf16 (dead after QKV)
  unsigned short* wf1T  = (unsigned short*)(ws + 6291456);    // 4096x1024 bf16
  unsigned short* wf2T  = (unsigned short*)(ws + 14680064);   // 1024x4096 bf16
  unsigned short* xb    = (unsigned short*)(ws + 23068672);   // 4096x1024 bf16 (dead after QKV)
  unsigned short* qkv   = (unsigned short*)(ws + 31457280);   // 4096x3072 bf16 (dead after attn)
  unsigned short* vt    = (unsigned short*)(ws + 56623104);   // 32x64x2048 bf16 (dead after attn)
  unsigned short* h1b   = (unsigned short*)(ws + 65011712);   // 4096x1024 bf16 (LN1 out)
  float* hpre           = (float*)(ws + 73400320);            // 4096x1024 f32 (FF2 slice 0)
  unsigned short* f1b   = (unsigned short*)(ws + 23068672);   // 4096x4096 bf16 (over xb+qkv)
  float* biasqkv        = (float*)(ws + 106954752);           // 3072 f32
  float* part_attn      = (float*)(ws + 106967040);           // 2*512*2 f32
  float* stats1         = (float*)(ws + 106977280);           // 2*2 f32
  float* ffpart2        = (float*)(ws);                       // 2*2048*2 f32 (over wqkvT, dead)
  float* stats2         = (float*)(ws + 65536);               // 2*2 f32 (over wqkvT, dead)

  // 1. conversions / transposes (Q path pre-scaled by 1/sqrt(dh)=0.125)
  k_f32_to_bf16<<<4096, 256, 0, stream>>>(x, xb, 4096 * 1024 / 4);
  k_transpose_w<<<dim3(16, 16), 256, 0, stream>>>(wq, wqkvT, 1024, 1024, 0.125f);
  k_transpose_w<<<dim3(16, 16), 256, 0, stream>>>(wk, wqkvT + 1024 * 1024, 1024, 1024, 1.0f);
  k_transpose_w<<<dim3(16, 16), 256, 0, stream>>>(wv, wqkvT + 2048 * 1024, 1024, 1024, 1.0f);
  k_transpose_w<<<dim3(16, 64), 256, 0, stream>>>(wf1, wf1T, 1024, 4096, 1.0f);
  k_transpose_w<<<dim3(64, 16), 256, 0, stream>>>(wf2, wf2T, 4096, 1024, 1.0f);
  k_concat3<<<12, 256, 0, stream>>>(bq, bk, bv, biasqkv, 1024, 0.125f);

  // 2. fused QKV projection: (4096x1024) @ (1024x3072), 16x12 = 192 blocks
  k_gemm8<0, 256><<<dim3(192, 1, 1), 512, 0, stream>>>(xb, 1024, wqkvT, 1024, biasqkv,
      qkv, nullptr, 3072, 1024, 12, 0);

  // 3. V transpose per head
  k_transpose_v<<<dim3(32, 32), 256, 0, stream>>>(qkv + 2048, 3072, vt, S, H);

  // 4. causal flash attention + x residual + LN1 partials
  //    grid (bh, qt): bh%8 pins each head's K/V to one XCD L2
  k_attn<<<dim3(32, 32), 256, 0, stream>>>(qkv, qkv + 1024, vt, 3072, x, hpre, part_attn, S, H);

  // 5. LN1 -> bf16 only
  k_ln_stats<<<2, 256, 0, stream>>>(part_attn, 512, stats1, 1.f / (2048.f * 1024.f));
  k_ln_apply<<<dim3(2048, 2), 256, 0, stream>>>(hpre, stats1, lng, lnb, nullptr, h1b, S * 1024);

  // 6. FF1: (4096x1024) @ (1024x4096), ReLU, 16x16 = 256 blocks
  k_gemm8<1, 256><<<dim3(256, 1, 1), 512, 0, stream>>>(h1b, 1024, wf1T, 1024, bf1,
      f1b, nullptr, 4096, 1024, 16, 0);

  // 7. FF2: (4096x4096) @ (4096x1024), 128x256 tiles, split-K=2 -> 256 blocks
  k_gemm8<3, 128><<<dim3(128, 1, 2), 512, 0, stream>>>(f1b, 4096, wf2T, 4096, nullptr,
      nullptr, hpre, 1024, 2048, 4, 4194304);

  // 8. reduce slices + bias + bf16 residual -> hpre, LN2 partials
  k_ff2_reduce<<<dim3(2048, 2), 256, 0, stream>>>(hpre, bf2, h1b, ffpart2);

  // 9. LN2 -> d_out (fp32)
  k_ln_stats<<<2, 256, 0, stream>>>(ffpart2, 2048, stats2, 1.f / (2048.f * 1024.f));
  k_ln_apply<<<dim3(2048, 2), 256, 0, stream>>>(hpre, stats2, ffg, ffb, (float*)d_out, nullptr, S * 1024);
}

// Round 5
// 237.155 us; speedup vs baseline: 1.6788x; 1.0868x over previous
//
#include <hip/hip_runtime.h>

typedef short s16x8 __attribute__((ext_vector_type(8)));
typedef float f32x4 __attribute__((ext_vector_type(4)));
typedef unsigned short u16x4 __attribute__((ext_vector_type(4)));

#define DEV static __device__ __forceinline__

DEV unsigned short f2bf(float f) {
  union { float f; unsigned u; } v; v.f = f;
  unsigned r = v.u + 0x7FFFu + ((v.u >> 16) & 1u);
  return (unsigned short)(r >> 16);
}
DEV float bf2f(unsigned short u) {
  union { unsigned u; float f; } v; v.u = (unsigned)u << 16; return v.f;
}

#define GLDS16(src, dst) \
  __builtin_amdgcn_global_load_lds((const __attribute__((address_space(1))) void*)(src), \
                                   (__attribute__((address_space(3))) void*)(dst), 16, 0, 0)

#define MFMA(a, b, c) __builtin_amdgcn_mfma_f32_16x16x32_bf16((a), (b), (c), 0, 0, 0)

// ---------------- elementwise fp32 -> bf16 ----------------
__global__ __launch_bounds__(256) void k_f32_to_bf16(const float* __restrict__ in,
                                                     unsigned short* __restrict__ out, int n4) {
  int i = blockIdx.x * 256 + threadIdx.x;
  if (i >= n4) return;
  float4 v = ((const float4*)in)[i];
  u16x4 o; o.x = f2bf(v.x); o.y = f2bf(v.y); o.z = f2bf(v.z); o.w = f2bf(v.w);
  ((u16x4*)out)[i] = o;
}

// ---------------- weight transpose+convert: (K,N) f32 -> (N,K) bf16, with scale ----------------
__global__ __launch_bounds__(256) void k_transpose_w(const float* __restrict__ W,
                                                     unsigned short* __restrict__ Wt,
                                                     int K, int N, float scale) {
  __shared__ float t[64][65];
  int k0 = blockIdx.x * 64, n0 = blockIdx.y * 64;
  int tid = threadIdx.x;
#pragma unroll
  for (int i = 0; i < 16; ++i) {
    int idx = tid + i * 256; int r = idx >> 6, c = idx & 63;
    t[r][c] = W[(size_t)(k0 + r) * N + (n0 + c)];
  }
  __syncthreads();
#pragma unroll
  for (int i = 0; i < 16; ++i) {
    int idx = tid + i * 256; int r = idx >> 6, c = idx & 63;
    Wt[(size_t)(n0 + r) * K + (k0 + c)] = f2bf(t[c][r] * scale);
  }
}

// ---------------- concat 3 bias vectors (a gets scale) ----------------
__global__ void k_concat3(const float* __restrict__ a, const float* __restrict__ b,
                          const float* __restrict__ c, float* __restrict__ out, int n, float sa) {
  int i = blockIdx.x * 256 + threadIdx.x;
  if (i >= 3 * n) return;
  int j = (i < n) ? i : (i < 2 * n ? i - n : i - 2 * n);
  out[i] = (i < n) ? a[j] * sa : (i < 2 * n ? b[j] : c[j]);
}

// ---------------- 256x256 4-phase pipelined GEMM: C = A(MxK) * Bt(NxK)^T ----------------
// BK=64 split into two k-half granules (256x32). 2 LDS tile-buffers (128 KiB).
// During tile t: stage Ak1,Bk1(t+1) in p1,p2 (other buf) and Ak0,Bk0(t+2) in
// p3,p4 (cur buf k0 region, closed by the end-p2 barrier). vmcnt(4) at end-p2
// (guarantees Ak0,Bk0(t+1)) and end-p4 (guarantees Ak1,Bk1(t+1)); barrier after
// each. 16-MFMA setprio clusters per phase. XOR-swizzled LDS (both-sides).
// MODE 0: bias -> bf16. MODE 1: bias+relu -> bf16.
// MODE 3: raw bf16 partial (no bias) at Cb + blockIdx.z*zstride, K = slice len.
template <int MODE>
__global__ __launch_bounds__(512, 2) void k_gemm8(
    const unsigned short* __restrict__ A, int lda,
    const unsigned short* __restrict__ Bt, int ldb,
    const float* __restrict__ bias,
    unsigned short* __restrict__ Cb, float* __restrict__ Cf, int ldc,
    int K, int nnt, size_t zstride) {
  __shared__ __align__(16) unsigned short As[2 * 2 * 8192];  // [buf][kh][256][32]
  __shared__ __align__(16) unsigned short Bs[2 * 2 * 8192];
  int nwg = gridDim.x;
  int bid = blockIdx.x;
  int cpx = nwg >> 3;                       // nwg % 8 == 0 for all our grids
  int swz = (bid & 7) * cpx + (bid >> 3);   // XCD-aware bijective swizzle
  int mt = swz / nnt, nt = swz % nnt;
  int m0 = mt * 256, n0 = nt * 256;
  int tid = threadIdx.x, w = tid >> 6, l = tid & 63;
  int wm = (w >> 2) * 128, wn = (w & 3) * 64;
  int kb = blockIdx.z * K;

  // staging: row sr = tid>>2 (and +128), phys granule gp = tid&3; slot (r,gp)
  // holds logical granule gp ^ ((r>>1)&3)  [involution]
  int sr = tid >> 2;
  int gsrc = (tid & 3) ^ ((sr >> 1) & 3);
  const unsigned short* Ag0 = A + (size_t)(m0 + sr) * lda + kb + gsrc * 8;
  const unsigned short* Ag1 = Ag0 + (size_t)128 * lda;
  const unsigned short* Bg0 = Bt + (size_t)(n0 + sr) * ldb + kb + gsrc * 8;
  const unsigned short* Bg1 = Bg0 + (size_t)128 * ldb;

  // granule (buf,kh) region: (buf*2+kh)*8192 elems; dest linear tid*8 (+4096)
#define STG_A(t, kh) do { int _c = (t) * 64 + (kh) * 32; int _d = ((((t) & 1) * 2 + (kh)) * 8192); \
    GLDS16(Ag0 + _c, &As[_d + tid * 8]); GLDS16(Ag1 + _c, &As[_d + 4096 + tid * 8]); } while (0)
#define STG_B(t, kh) do { int _c = (t) * 64 + (kh) * 32; int _d = ((((t) & 1) * 2 + (kh)) * 8192); \
    GLDS16(Bg0 + _c, &Bs[_d + tid * 8]); GLDS16(Bg1 + _c, &Bs[_d + 4096 + tid * 8]); } while (0)

  // fragment reads: row = wm/wn + (mh*64) + fr*16 + (l&15); logical k-granule l>>4
  int lswz = (l >> 1) & 3;
  int acol = ((l >> 4) ^ lswz) * 8;
  const unsigned short* Afr = &As[(wm + (l & 15)) * 32 + acol];
  const unsigned short* Bfr = &Bs[(wn + (l & 15)) * 32 + acol];

  f32x4 acc[8][4] = {};
  int nkt = K >> 6;

  // prologue: tile0 (all 4 granules) + Ak0,Bk0(1) = 12 loads; retire tile0
  STG_A(0, 0); STG_B(0, 0); STG_A(0, 1); STG_B(0, 1); STG_A(1, 0); STG_B(1, 0);
  asm volatile("s_waitcnt vmcnt(4)" ::: "memory");
  __builtin_amdgcn_s_barrier();
  __builtin_amdgcn_sched_barrier(0);

  for (int t = 0; t < nkt; ++t) {
    int cur = t & 1, rem = nkt - t;
    const unsigned short* ab = Afr + cur * 16384;
    const unsigned short* bb = Bfr + cur * 16384;
    s16x8 af[4], bf[4];
    // ---- p1: (mhalf0, k0) ----
    if (t + 1 < nkt) STG_A(t + 1, 1);
#pragma unroll
    for (int nr = 0; nr < 4; ++nr) bf[nr] = *(const s16x8*)(bb + nr * 512);
#pragma unroll
    for (int mr = 0; mr < 4; ++mr) af[mr] = *(const s16x8*)(ab + mr * 512);
    __builtin_amdgcn_s_setprio(1);
#pragma unroll
    for (int mr = 0; mr < 4; ++mr)
#pragma unroll
      for (int nr = 0; nr < 4; ++nr)
        acc[mr][nr] = MFMA(af[mr], bf[nr], acc[mr][nr]);
    __builtin_amdgcn_s_setprio(0);
    // ---- p2: (mhalf1, k0) ----
    if (t + 1 < nkt) STG_B(t + 1, 1);
#pragma unroll
    for (int mr = 0; mr < 4; ++mr) af[mr] = *(const s16x8*)(ab + 2048 + mr * 512);
    __builtin_amdgcn_s_setprio(1);
#pragma unroll
    for (int mr = 0; mr < 4; ++mr)
#pragma unroll
      for (int nr = 0; nr < 4; ++nr)
        acc[mr + 4][nr] = MFMA(af[mr], bf[nr], acc[mr + 4][nr]);
    __builtin_amdgcn_s_setprio(0);
    if (rem >= 2) { asm volatile("s_waitcnt vmcnt(4)" ::: "memory"); }
    else          { asm volatile("s_waitcnt vmcnt(0)" ::: "memory"); }
    __builtin_amdgcn_s_barrier();
    __builtin_amdgcn_sched_barrier(0);
    // ---- p3: (mhalf0, k1) ----
    if (t + 2 < nkt) STG_A(t + 2, 0);
#pragma unroll
    for (int nr = 0; nr < 4; ++nr) bf[nr] = *(const s16x8*)(bb + 8192 + nr * 512);
#pragma unroll
    for (int mr = 0; mr < 4; ++mr) af[mr] = *(const s16x8*)(ab + 8192 + mr * 512);
    __builtin_amdgcn_s_setprio(1);
#pragma unroll
    for (int mr = 0; mr < 4; ++mr)
#pragma unroll
      for (int nr = 0; nr < 4; ++nr)
        acc[mr][nr] = MFMA(af[mr], bf[nr], acc[mr][nr]);
    __builtin_amdgcn_s_setprio(0);
    // ---- p4: (mhalf1, k1) ----
    if (t + 2 < nkt) STG_B(t + 2, 0);
#pragma unroll
    for (int mr = 0; mr < 4; ++mr) af[mr] = *(const s16x8*)(ab + 8192 + 2048 + mr * 512);
    __builtin_amdgcn_s_setprio(1);
#pragma unroll
    for (int mr = 0; mr < 4; ++mr)
#pragma unroll
      for (int nr = 0; nr < 4; ++nr)
        acc[mr + 4][nr] = MFMA(af[mr], bf[nr], acc[mr + 4][nr]);
    __builtin_amdgcn_s_setprio(0);
    if (rem >= 3) { asm volatile("s_waitcnt vmcnt(4)" ::: "memory"); }
    else          { asm volatile("s_waitcnt vmcnt(0)" ::: "memory"); }
    __builtin_amdgcn_s_barrier();
    __builtin_amdgcn_sched_barrier(0);
  }
#undef STG_A
#undef STG_B

  unsigned short* Cbz = (MODE == 3) ? (Cb + zstride * blockIdx.z) : Cb;
#pragma unroll
  for (int mr = 0; mr < 8; ++mr) {
    int rb = m0 + wm + mr * 16 + (l >> 4) * 4;
#pragma unroll
    for (int nr = 0; nr < 4; ++nr) {
      int col = n0 + wn + nr * 16 + (l & 15);
      float bv = (MODE == 3) ? 0.f : bias[col];
#pragma unroll
      for (int j = 0; j < 4; ++j) {
        float v = acc[mr][nr][j] + bv;
        size_t off = (size_t)(rb + j) * ldc + col;
        if (MODE == 1) v = fmaxf(v, 0.f);
        Cbz[off] = f2bf(v);
      }
    }
  }
}

// ---------------- FF2 split-K=4 reduce (row-interleaved bf16 slices) ----------------
// Block i: read slice rows [i*4 .. i*4+3] (8 KB), sum + bias + bf16 residual,
// write f32 row at (float*)slices + i*2048 (first 4 KB of the same range,
// after __syncthreads) + LN2 partials. Deterministic, block-local.
__global__ __launch_bounds__(256) void k_ff2_reduce(
    unsigned short* __restrict__ slices, const float* __restrict__ bias,
    const unsigned short* __restrict__ resid, float* __restrict__ partials) {
  __shared__ float red[8];
  int i = blockIdx.x;                  // global row 0..4095
  size_t rb = (size_t)i * 4096;
  int c = threadIdx.x * 4;
  u16x4 a0 = *(const u16x4*)(slices + rb + c);
  u16x4 a1 = *(const u16x4*)(slices + rb + 1024 + c);
  u16x4 a2 = *(const u16x4*)(slices + rb + 2048 + c);
  u16x4 a3 = *(const u16x4*)(slices + rb + 3072 + c);
  float4 bv = *(const float4*)(bias + c);
  u16x4 rv = *(const u16x4*)(resid + (size_t)i * 1024 + c);
  float4 o;
  o.x = bf2f(a0.x) + bf2f(a1.x) + bf2f(a2.x) + bf2f(a3.x) + bv.x + bf2f(rv.x);
  o.y = bf2f(a0.y) + bf2f(a1.y) + bf2f(a2.y) + bf2f(a3.y) + bv.y + bf2f(rv.y);
  o.z = bf2f(a0.z) + bf2f(a1.z) + bf2f(a2.z) + bf2f(a3.z) + bv.z + bf2f(rv.z);
  o.w = bf2f(a0.w) + bf2f(a1.w) + bf2f(a2.w) + bf2f(a3.w) + bv.w + bf2f(rv.w);
  __syncthreads();
  *(float4*)((float*)slices + (size_t)i * 2048 + c) = o;
  float bsum = o.x + o.y + o.z + o.w;
  float bsq = o.x * o.x + o.y * o.y + o.z * o.z + o.w * o.w;
  int wv = threadIdx.x >> 6, lv = threadIdx.x & 63;
#pragma unroll
  for (int mk = 1; mk < 64; mk <<= 1) { bsum += __shfl_xor(bsum, mk); bsq += __shfl_xor(bsq, mk); }
  if (lv == 0) { red[wv] = bsum; red[4 + wv] = bsq; }
  __syncthreads();
  if (threadIdx.x == 0) {
    partials[i * 2] = red[0] + red[1] + red[2] + red[3];
    partials[i * 2 + 1] = red[4] + red[5] + red[6] + red[7];
  }
}

// ---------------- V transpose per head: (s, d) -> (d, s), bf16 ----------------
__global__ __launch_bounds__(256) void k_transpose_v(const unsigned short* __restrict__ V, int ldv,
                                                     unsigned short* __restrict__ Vt, int S, int H) {
  __shared__ __align__(16) unsigned short t[64][72];
  int s0 = blockIdx.x * 64;
  int bh = blockIdx.y; int b = bh / H, h = bh % H;
  const unsigned short* src = V + (size_t)(b * S) * ldv + h * 64;
  unsigned short* dst = Vt + (size_t)bh * 64 * S;
  int tid = threadIdx.x;
#pragma unroll
  for (int i = 0; i < 2; ++i) {
    int idx = tid + i * 256;
    int s = idx >> 3, c = (idx & 7) * 8;
    s16x8 v = *(const s16x8*)(src + (size_t)(s0 + s) * ldv + c);
#pragma unroll
    for (int j = 0; j < 8; ++j) t[c + j][s] = (unsigned short)v[j];
  }
  __syncthreads();
#pragma unroll
  for (int i = 0; i < 2; ++i) {
    int idx = tid + i * 256;
    int d = idx >> 3, c = (idx & 7) * 8;
    *(s16x8*)(dst + (size_t)d * S + s0 + c) = *(const s16x8*)&t[d][c];
  }
}

// ---------------- causal flash attention + residual + LN partials ----------------
__global__ __launch_bounds__(256) void k_attn(
    const unsigned short* __restrict__ Qg, const unsigned short* __restrict__ Kg,
    const unsigned short* __restrict__ Vt, int ldqk,
    const float* __restrict__ x, float* __restrict__ hpre,
    float* __restrict__ partials, int S, int H) {
  __shared__ __align__(16) unsigned short Ks[2][64 * 64];
  __shared__ __align__(16) unsigned short Vs[2][64 * 64];
  __shared__ __align__(16) unsigned short Ps[4][16 * 64];
  __shared__ float red[8];
  int bh = blockIdx.x, b = bh >> 4, h = bh & 15;
  const int nqt = S / 64;
  int qt = nqt - 1 - (int)blockIdx.y;   // heavy tiles dispatched first
  int tid = threadIdx.x, w = tid >> 6, l = tid & 63;
  const int U = H * 64;
  const unsigned short* Qb = Qg + (size_t)(b * S) * ldqk + h * 64;
  const unsigned short* Kb = Kg + (size_t)(b * S) * ldqk + h * 64;
  const unsigned short* Vb = Vt + (size_t)bh * 64 * S;
  const float* xb = x + (size_t)(b * S) * U + h * 64;
  float* hb = hpre + (size_t)(b * S) * U + h * 64;
  int sg_r[2], sg_c[2];
#pragma unroll
  for (int it = 0; it < 2; ++it) {
    int g = it * 256 + tid;
    sg_r[it] = g >> 3;
    sg_c[it] = ((g & 7) ^ ((g >> 3) & 7)) * 8;
  }
  unsigned short* Pw = &Ps[w][0];
  int qloc = l & 15;
  int kloc = (l >> 4) * 4;

  int qrow = qt * 64 + w * 16 + qloc;
  s16x8 qf0 = *(const s16x8*)(Qb + (size_t)qrow * ldqk + (l >> 4) * 8);
  s16x8 qf1 = *(const s16x8*)(Qb + (size_t)qrow * ldqk + 32 + (l >> 4) * 8);
  f32x4 o[4] = {};
  float m = -1e30f, lsum = 0.f;

#pragma unroll
  for (int it = 0; it < 2; ++it) {
    GLDS16(Kb + (size_t)sg_r[it] * ldqk + sg_c[it], &Ks[0][(it * 256 + tid) * 8]);
    GLDS16(Vb + (size_t)sg_r[it] * S + sg_c[it], &Vs[0][(it * 256 + tid) * 8]);
  }

  for (int kt = 0; kt <= qt; ++kt) {
    int cur = kt & 1;
    __syncthreads();
    if (kt < qt) {
      int nb = cur ^ 1, kn = (kt + 1) * 64;
#pragma unroll
      for (int it = 0; it < 2; ++it) {
        GLDS16(Kb + (size_t)(kn + sg_r[it]) * ldqk + sg_c[it], &Ks[nb][(it * 256 + tid) * 8]);
        GLDS16(Vb + (size_t)sg_r[it] * S + kn + sg_c[it], &Vs[nb][(it * 256 + tid) * 8]);
      }
    }
    f32x4 sc[4];
    __builtin_amdgcn_s_setprio(1);
#pragma unroll
    for (int fn = 0; fn < 4; ++fn) {
      int row = fn * 16 + (l & 15);
      s16x8 kf0 = *(const s16x8*)&Ks[cur][row * 64 + ((((l >> 4)) ^ (row & 7)) * 8)];
      s16x8 kf1 = *(const s16x8*)&Ks[cur][row * 64 + (((4 + (l >> 4)) ^ (row & 7)) * 8)];
      f32x4 z = {};
      z = MFMA(kf0, qf0, z);
      z = MFMA(kf1, qf1, z);
      sc[fn] = z;
    }
    __builtin_amdgcn_s_setprio(0);
    if (kt == qt) {
      int qsel = w * 16 + qloc;
#pragma unroll
      for (int fn = 0; fn < 4; ++fn)
#pragma unroll
        for (int j = 0; j < 4; ++j)
          if (fn * 16 + kloc + j > qsel) sc[fn][j] = -1e30f;
    }
    float mx = sc[0][0];
#pragma unroll
    for (int fn = 0; fn < 4; ++fn)
#pragma unroll
      for (int j = 0; j < 4; ++j) mx = fmaxf(mx, sc[fn][j]);
    mx = fmaxf(mx, __shfl_xor(mx, 16));
    mx = fmaxf(mx, __shfl_xor(mx, 32));
    if (__ballot(mx > m + 8.f)) {
      float mnew = fmaxf(m, mx);
      float alpha = __expf(m - mnew);
      m = mnew;
      lsum *= alpha;
#pragma unroll
      for (int j = 0; j < 4; ++j) {
        float aj = __shfl(alpha, (l & 48) | (kloc + j));
#pragma unroll
        for (int fd = 0; fd < 4; ++fd) o[fd][j] *= aj;
      }
    }
    float rs = 0.f;
#pragma unroll
    for (int fn = 0; fn < 4; ++fn) {
      u16x4 pk;
#pragma unroll
      for (int j = 0; j < 4; ++j) {
        float p = __expf(sc[fn][j] - m);
        rs += p;
        ((unsigned short*)&pk)[j] = f2bf(p);
      }
      int kb2 = fn * 16 + kloc;
      int el = qloc * 64 + (((kb2 >> 3) ^ (qloc & 7)) * 8) + (kb2 & 7);
      *(u16x4*)&Pw[el] = pk;
    }
    rs += __shfl_xor(rs, 16);
    rs += __shfl_xor(rs, 32);
    lsum += rs;
    __builtin_amdgcn_s_setprio(1);
#pragma unroll
    for (int kk = 0; kk < 2; ++kk) {
      int prow = l & 15;
      s16x8 pa = *(const s16x8*)&Pw[prow * 64 + (((kk * 4 + (l >> 4)) ^ (prow & 7)) * 8)];
#pragma unroll
      for (int fd = 0; fd < 4; ++fd) {
        int vrow = fd * 16 + (l & 15);
        s16x8 vf = *(const s16x8*)&Vs[cur][vrow * 64 + (((kk * 4 + (l >> 4)) ^ (vrow & 7)) * 8)];
        o[fd] = MFMA(pa, vf, o[fd]);
      }
    }
    __builtin_amdgcn_s_setprio(0);
  }
  float bsum = 0.f, bsq = 0.f;
#pragma unroll
  for (int j = 0; j < 4; ++j) {
    float lr = __shfl(lsum, (l & 48) | (kloc + j));
    float inv = 1.f / lr;
    int row = qt * 64 + w * 16 + kloc + j;
#pragma unroll
    for (int fd = 0; fd < 4; ++fd) {
      int col = fd * 16 + (l & 15);
      float v = o[fd][j] * inv + xb[(size_t)row * U + col];
      hb[(size_t)row * U + col] = v;
      bsum += v; bsq += v * v;
    }
  }
#pragma unroll
  for (int mk = 1; mk < 64; mk <<= 1) { bsum += __shfl_xor(bsum, mk); bsq += __shfl_xor(bsq, mk); }
  if (l == 0) { red[w] = bsum; red[4 + w] = bsq; }
  __syncthreads();
  if (tid == 0) {
    float s2 = red[0] + red[1] + red[2] + red[3];
    float q2 = red[4] + red[5] + red[6] + red[7];
    int pi = b * (H * nqt) + h * nqt + qt;
    partials[pi * 2] = s2; partials[pi * 2 + 1] = q2;
  }
}

// ---------------- LN over (S,U) per batch ----------------
__global__ __launch_bounds__(256) void k_ln_stats(const float* __restrict__ partials, int nper,
                                                  float* __restrict__ stats, float invN) {
  int b = blockIdx.x, tid = threadIdx.x;
  float s = 0.f, q = 0.f;
  for (int i = tid; i < nper; i += 256) { s += partials[(b * nper + i) * 2]; q += partials[(b * nper + i) * 2 + 1]; }
#pragma unroll
  for (int mk = 1; mk < 64; mk <<= 1) { s += __shfl_xor(s, mk); q += __shfl_xor(q, mk); }
  __shared__ float red[8];
  int w = tid >> 6, l = tid & 63;
  if (l == 0) { red[w] = s; red[4 + w] = q; }
  __syncthreads();
  if (tid == 0) {
    s = red[0] + red[1] + red[2] + red[3];
    q = red[4] + red[5] + red[6] + red[7];
    float m = s * invN, var = q * invN - m * m;
    stats[b * 2] = m; stats[b * 2 + 1] = rsqrtf(var + 1e-5f);
  }
}

__global__ __launch_bounds__(256) void k_ln_apply(
    const float* __restrict__ src, const float* __restrict__ stats,
    const float* __restrict__ g, const float* __restrict__ bt,
    float* __restrict__ outf, unsigned short* __restrict__ outb, int SU) {
  int b = blockIdx.y;
  int idx = (blockIdx.x * 256 + threadIdx.x) * 4;
  float m = stats[b * 2], r = stats[b * 2 + 1];
  float4 v = *(const float4*)(src + (size_t)b * SU + idx);
  float4 gg = *(const float4*)(g + idx);
  float4 bb = *(const float4*)(bt + idx);
  float4 o;
  o.x = (v.x - m) * r * gg.x + bb.x;
  o.y = (v.y - m) * r * gg.y + bb.y;
  o.z = (v.z - m) * r * gg.z + bb.z;
  o.w = (v.w - m) * r * gg.w + bb.w;
  if (outf) *(float4*)(outf + (size_t)b * SU + idx) = o;
  if (outb) {
    u16x4 ob; ob.x = f2bf(o.x); ob.y = f2bf(o.y); ob.z = f2bf(o.z); ob.w = f2bf(o.w);
    *(u16x4*)(outb + (size_t)b * SU + idx) = ob;
  }
}

// LN apply from stride-2048 f32 rows (FF2 reduce output) -> d_out
__global__ __launch_bounds__(256) void k_ln_apply2(
    const float* __restrict__ src, const float* __restrict__ stats,
    const float* __restrict__ g, const float* __restrict__ bt,
    float* __restrict__ outf) {
  int b = blockIdx.y;
  int row = blockIdx.x;                 // 0..2047 within batch
  int grow = b * 2048 + row;
  int c = threadIdx.x * 4;
  float m = stats[b * 2], r = stats[b * 2 + 1];
  float4 v = *(const float4*)(src + (size_t)grow * 2048 + c);
  float4 gg = *(const float4*)(g + (size_t)row * 1024 + c);
  float4 bb = *(const float4*)(bt + (size_t)row * 1024 + c);
  float4 o;
  o.x = (v.x - m) * r * gg.x + bb.x;
  o.y = (v.y - m) * r * gg.y + bb.y;
  o.z = (v.z - m) * r * gg.z + bb.z;
  o.w = (v.w - m) * r * gg.w + bb.w;
  *(float4*)(outf + (size_t)grow * 1024 + c) = o;
}

extern "C" void kernel_launch(void* const* d_in, const int* in_sizes, int n_in,
                              void* d_out, int out_size, void* d_ws, size_t ws_size,
                              hipStream_t stream) {
  (void)in_sizes; (void)n_in; (void)out_size; (void)ws_size;
  const int S = 2048, H = 16;
  const float* x   = (const float*)d_in[0];
  const float* wq  = (const float*)d_in[1];
  const float* bq  = (const float*)d_in[2];
  const float* wk  = (const float*)d_in[3];
  const float* bk  = (const float*)d_in[4];
  const float* wv  = (const float*)d_in[5];
  const float* bv  = (const float*)d_in[6];
  const float* wf1 = (const float*)d_in[7];
  const float* bf1 = (const float*)d_in[8];
  const float* wf2 = (const float*)d_in[9];
  const float* bf2 = (const float*)d_in[10];
  const float* lng = (const float*)d_in[11];
  const float* lnb = (const float*)d_in[12];
  const float* ffg = (const float*)d_in[13];
  const float* ffb = (const float*)d_in[14];

  char* ws = (char*)d_ws;
  unsigned short* wqkvT = (unsigned short*)(ws);              // 3072x1024 bf16 (dead after QKV)
  unsigned short* wf1T  = (unsigned short*)(ws + 6291456);    // 4096x1024 bf16 (dead after FF1)
  unsigned short* wf2T  = (unsigned short*)(ws + 14680064);   // 1024x4096 bf16
  unsigned short* xb    = (unsigned short*)(ws + 23068672);   // 4096x1024 bf16 (dead after QKV)
  unsigned short* qkv   = (unsigned short*)(ws + 31457280);   // 4096x3072 bf16 (dead after attn)
  unsigned short* vt    = (unsigned short*)(ws + 56623104);   // 32x64x2048 bf16 (dead after attn)
  unsigned short* h1b   = (unsigned short*)(ws + 65011712);   // 4096x1024 bf16 (LN1 out)
  float* hpre           = (float*)(ws + 73400320);            // 4096x1024 f32 (dead after LN1)
  unsigned short* ff2s  = (unsigned short*)(ws + 73400320);   // FF2 slices: 4096 x 4096 bf16 (33.55 MB, over hpre+)
  unsigned short* f1b   = (unsigned short*)(ws + 23068672);   // 4096x4096 bf16 (over xb+qkv)
  float* biasqkv        = (float*)(ws + 106954752);           // 3072 f32
  float* part_attn      = (float*)(ws + 106967040);           // 2*512*2 f32
  float* stats1         = (float*)(ws + 106977280);           // 2*2 f32
  float* ffpart2        = (float*)(ws);                       // 4096*2 f32 (over wqkvT, dead)
  float* stats2         = (float*)(ws + 65536);               // 2*2 f32 (over wqkvT, dead)

  // 1. conversions / transposes (Q path pre-scaled by 1/sqrt(dh)=0.125)
  k_f32_to_bf16<<<4096, 256, 0, stream>>>(x, xb, 4096 * 1024 / 4);
  k_transpose_w<<<dim3(16, 16), 256, 0, stream>>>(wq, wqkvT, 1024, 1024, 0.125f);
  k_transpose_w<<<dim3(16, 16), 256, 0, stream>>>(wk, wqkvT + 1024 * 1024, 1024, 1024, 1.0f);
  k_transpose_w<<<dim3(16, 16), 256, 0, stream>>>(wv, wqkvT + 2048 * 1024, 1024, 1024, 1.0f);
  k_transpose_w<<<dim3(16, 64), 256, 0, stream>>>(wf1, wf1T, 1024, 4096, 1.0f);
  k_transpose_w<<<dim3(64, 16), 256, 0, stream>>>(wf2, wf2T, 4096, 1024, 1.0f);
  k_concat3<<<12, 256, 0, stream>>>(bq, bk, bv, biasqkv, 1024, 0.125f);

  // 2. fused QKV projection: (4096x1024) @ (1024x3072), 16x12 = 192 blocks
  k_gemm8<0><<<dim3(192, 1, 1), 512, 0, stream>>>(xb, 1024, wqkvT, 1024, biasqkv,
      qkv, nullptr, 3072, 1024, 12, 0);

  // 3. V transpose per head
  k_transpose_v<<<dim3(32, 32), 256, 0, stream>>>(qkv + 2048, 3072, vt, S, H);

  // 4. causal flash attention + x residual + LN1 partials
  k_attn<<<dim3(32, 32), 256, 0, stream>>>(qkv, qkv + 1024, vt, 3072, x, hpre, part_attn, S, H);

  // 5. LN1 -> bf16 only
  k_ln_stats<<<2, 256, 0, stream>>>(part_attn, 512, stats1, 1.f / (2048.f * 1024.f));
  k_ln_apply<<<dim3(2048, 2), 256, 0, stream>>>(hpre, stats1, lng, lnb, nullptr, h1b, S * 1024);

  // 6. FF1: (4096x1024) @ (1024x4096), ReLU, 16x16 = 256 blocks
  k_gemm8<1><<<dim3(256, 1, 1), 512, 0, stream>>>(h1b, 1024, wf1T, 1024, bf1,
      f1b, nullptr, 4096, 1024, 16, 0);

  // 7. FF2: (4096x4096) @ (4096x1024), split-K=4 -> 64x4 = 256 blocks,
  //    bf16 row-interleaved slices (slice z row i at ff2s + i*4096 + z*1024)
  k_gemm8<3><<<dim3(64, 1, 4), 512, 0, stream>>>(f1b, 4096, wf2T, 4096, nullptr,
      ff2s, nullptr, 4096, 1024, 4, 1024);

  // 8. reduce slices + bias + bf16 residual -> f32 rows (stride 2048), LN2 partials
  k_ff2_reduce<<<4096, 256, 0, stream>>>(ff2s, bf2, h1b, ffpart2);

  // 9. LN2 -> d_out (fp32)
  k_ln_stats<<<2, 256, 0, stream>>>(ffpart2, 2048, stats2, 1.f / (2048.f * 1024.f));
  k_ln_apply2<<<dim3(2048, 2), 256, 0, stream>>>((float*)ff2s, stats2, ffg, ffb, (float*)d_out);
}

// Round 6
// 236.168 us; speedup vs baseline: 1.6858x; 1.0042x over previous
//
#include <hip/hip_runtime.h>
#include <hip/hip_bf16.h>

typedef short s16x8 __attribute__((ext_vector_type(8)));
typedef float f32x4 __attribute__((ext_vector_type(4)));
typedef unsigned short u16x4 __attribute__((ext_vector_type(4)));

#define DEV static __device__ __forceinline__

DEV unsigned short f2bf(float f) {  // native cast -> compiler packs pairs into v_cvt_pk_bf16_f32
  __hip_bfloat16 h = __float2bfloat16(f);
  return *reinterpret_cast<unsigned short*>(&h);
}
DEV float bf2f(unsigned short u) {
  union { unsigned u; float f; } v; v.u = (unsigned)u << 16; return v.f;
}

#define GLDS16(src, dst) \
  __builtin_amdgcn_global_load_lds((const __attribute__((address_space(1))) void*)(src), \
                                   (__attribute__((address_space(3))) void*)(dst), 16, 0, 0)

#define MFMA(a, b, c) __builtin_amdgcn_mfma_f32_16x16x32_bf16((a), (b), (c), 0, 0, 0)

// ---------------- elementwise fp32 -> bf16 ----------------
__global__ __launch_bounds__(256) void k_f32_to_bf16(const float* __restrict__ in,
                                                     unsigned short* __restrict__ out, int n4) {
  int i = blockIdx.x * 256 + threadIdx.x;
  if (i >= n4) return;
  float4 v = ((const float4*)in)[i];
  u16x4 o; o.x = f2bf(v.x); o.y = f2bf(v.y); o.z = f2bf(v.z); o.w = f2bf(v.w);
  ((u16x4*)out)[i] = o;
}

// ---------------- weight transpose+convert: (K,N) f32 -> (N,K) bf16, with scale ----------------
__global__ __launch_bounds__(256) void k_transpose_w(const float* __restrict__ W,
                                                     unsigned short* __restrict__ Wt,
                                                     int K, int N, float scale) {
  __shared__ float t[64][65];
  int k0 = blockIdx.x * 64, n0 = blockIdx.y * 64;
  int tid = threadIdx.x;
#pragma unroll
  for (int i = 0; i < 16; ++i) {
    int idx = tid + i * 256; int r = idx >> 6, c = idx & 63;
    t[r][c] = W[(size_t)(k0 + r) * N + (n0 + c)];
  }
  __syncthreads();
#pragma unroll
  for (int i = 0; i < 16; ++i) {
    int idx = tid + i * 256; int r = idx >> 6, c = idx & 63;
    Wt[(size_t)(n0 + r) * K + (k0 + c)] = f2bf(t[c][r] * scale);
  }
}

// ---------------- concat 3 bias vectors (a gets scale) ----------------
__global__ void k_concat3(const float* __restrict__ a, const float* __restrict__ b,
                          const float* __restrict__ c, float* __restrict__ out, int n, float sa) {
  int i = blockIdx.x * 256 + threadIdx.x;
  if (i >= 3 * n) return;
  int j = (i < n) ? i : (i < 2 * n ? i - n : i - 2 * n);
  out[i] = (i < n) ? a[j] * sa : (i < 2 * n ? b[j] : c[j]);
}

// ---------------- 256x256 4-phase pipelined GEMM: C = A(MxK) * Bt(NxK)^T ----------------
// BK=64, two k-half granules, 2 LDS tile-buffers, counted vmcnt(4), setprio
// clusters, XOR-swizzled LDS (both-sides), XCD block swizzle. See round 5.
template <int MODE>
__global__ __launch_bounds__(512, 2) void k_gemm8(
    const unsigned short* __restrict__ A, int lda,
    const unsigned short* __restrict__ Bt, int ldb,
    const float* __restrict__ bias,
    unsigned short* __restrict__ Cb, float* __restrict__ Cf, int ldc,
    int K, int nnt, size_t zstride) {
  __shared__ __align__(16) unsigned short As[2 * 2 * 8192];  // [buf][kh][256][32]
  __shared__ __align__(16) unsigned short Bs[2 * 2 * 8192];
  int nwg = gridDim.x;
  int bid = blockIdx.x;
  int cpx = nwg >> 3;
  int swz = (bid & 7) * cpx + (bid >> 3);
  int mt = swz / nnt, nt = swz % nnt;
  int m0 = mt * 256, n0 = nt * 256;
  int tid = threadIdx.x, w = tid >> 6, l = tid & 63;
  int wm = (w >> 2) * 128, wn = (w & 3) * 64;
  int kb = blockIdx.z * K;

  int sr = tid >> 2;
  int gsrc = (tid & 3) ^ ((sr >> 1) & 3);
  const unsigned short* Ag0 = A + (size_t)(m0 + sr) * lda + kb + gsrc * 8;
  const unsigned short* Ag1 = Ag0 + (size_t)128 * lda;
  const unsigned short* Bg0 = Bt + (size_t)(n0 + sr) * ldb + kb + gsrc * 8;
  const unsigned short* Bg1 = Bg0 + (size_t)128 * ldb;

#define STG_A(t, kh) do { int _c = (t) * 64 + (kh) * 32; int _d = ((((t) & 1) * 2 + (kh)) * 8192); \
    GLDS16(Ag0 + _c, &As[_d + tid * 8]); GLDS16(Ag1 + _c, &As[_d + 4096 + tid * 8]); } while (0)
#define STG_B(t, kh) do { int _c = (t) * 64 + (kh) * 32; int _d = ((((t) & 1) * 2 + (kh)) * 8192); \
    GLDS16(Bg0 + _c, &Bs[_d + tid * 8]); GLDS16(Bg1 + _c, &Bs[_d + 4096 + tid * 8]); } while (0)

  int lswz = (l >> 1) & 3;
  int acol = ((l >> 4) ^ lswz) * 8;
  const unsigned short* Afr = &As[(wm + (l & 15)) * 32 + acol];
  const unsigned short* Bfr = &Bs[(wn + (l & 15)) * 32 + acol];

  f32x4 acc[8][4] = {};
  int nkt = K >> 6;

  STG_A(0, 0); STG_B(0, 0); STG_A(0, 1); STG_B(0, 1); STG_A(1, 0); STG_B(1, 0);
  asm volatile("s_waitcnt vmcnt(4)" ::: "memory");
  __builtin_amdgcn_s_barrier();
  __builtin_amdgcn_sched_barrier(0);

  for (int t = 0; t < nkt; ++t) {
    int cur = t & 1, rem = nkt - t;
    const unsigned short* ab = Afr + cur * 16384;
    const unsigned short* bb = Bfr + cur * 16384;
    s16x8 af[4], bf[4];
    // ---- p1: (mhalf0, k0) ----
    if (t + 1 < nkt) STG_A(t + 1, 1);
#pragma unroll
    for (int nr = 0; nr < 4; ++nr) bf[nr] = *(const s16x8*)(bb + nr * 512);
#pragma unroll
    for (int mr = 0; mr < 4; ++mr) af[mr] = *(const s16x8*)(ab + mr * 512);
    __builtin_amdgcn_s_setprio(1);
#pragma unroll
    for (int mr = 0; mr < 4; ++mr)
#pragma unroll
      for (int nr = 0; nr < 4; ++nr)
        acc[mr][nr] = MFMA(af[mr], bf[nr], acc[mr][nr]);
    __builtin_amdgcn_s_setprio(0);
    // ---- p2: (mhalf1, k0) ----
    if (t + 1 < nkt) STG_B(t + 1, 1);
#pragma unroll
    for (int mr = 0; mr < 4; ++mr) af[mr] = *(const s16x8*)(ab + 2048 + mr * 512);
    __builtin_amdgcn_s_setprio(1);
#pragma unroll
    for (int mr = 0; mr < 4; ++mr)
#pragma unroll
      for (int nr = 0; nr < 4; ++nr)
        acc[mr + 4][nr] = MFMA(af[mr], bf[nr], acc[mr + 4][nr]);
    __builtin_amdgcn_s_setprio(0);
    if (rem >= 2) { asm volatile("s_waitcnt vmcnt(4)" ::: "memory"); }
    else          { asm volatile("s_waitcnt vmcnt(0)" ::: "memory"); }
    __builtin_amdgcn_s_barrier();
    __builtin_amdgcn_sched_barrier(0);
    // ---- p3: (mhalf0, k1) ----
    if (t + 2 < nkt) STG_A(t + 2, 0);
#pragma unroll
    for (int nr = 0; nr < 4; ++nr) bf[nr] = *(const s16x8*)(bb + 8192 + nr * 512);
#pragma unroll
    for (int mr = 0; mr < 4; ++mr) af[mr] = *(const s16x8*)(ab + 8192 + mr * 512);
    __builtin_amdgcn_s_setprio(1);
#pragma unroll
    for (int mr = 0; mr < 4; ++mr)
#pragma unroll
      for (int nr = 0; nr < 4; ++nr)
        acc[mr][nr] = MFMA(af[mr], bf[nr], acc[mr][nr]);
    __builtin_amdgcn_s_setprio(0);
    // ---- p4: (mhalf1, k1) ----
    if (t + 2 < nkt) STG_B(t + 2, 0);
#pragma unroll
    for (int mr = 0; mr < 4; ++mr) af[mr] = *(const s16x8*)(ab + 8192 + 2048 + mr * 512);
    __builtin_amdgcn_s_setprio(1);
#pragma unroll
    for (int mr = 0; mr < 4; ++mr)
#pragma unroll
      for (int nr = 0; nr < 4; ++nr)
        acc[mr + 4][nr] = MFMA(af[mr], bf[nr], acc[mr + 4][nr]);
    __builtin_amdgcn_s_setprio(0);
    if (rem >= 3) { asm volatile("s_waitcnt vmcnt(4)" ::: "memory"); }
    else          { asm volatile("s_waitcnt vmcnt(0)" ::: "memory"); }
    __builtin_amdgcn_s_barrier();
    __builtin_amdgcn_sched_barrier(0);
  }
#undef STG_A
#undef STG_B

  unsigned short* Cbz = (MODE == 3) ? (Cb + zstride * blockIdx.z) : Cb;
#pragma unroll
  for (int mr = 0; mr < 8; ++mr) {
    int rb = m0 + wm + mr * 16 + (l >> 4) * 4;
#pragma unroll
    for (int nr = 0; nr < 4; ++nr) {
      int col = n0 + wn + nr * 16 + (l & 15);
      float bv = (MODE == 3) ? 0.f : bias[col];
#pragma unroll
      for (int j = 0; j < 4; ++j) {
        float v = acc[mr][nr][j] + bv;
        size_t off = (size_t)(rb + j) * ldc + col;
        if (MODE == 1) v = fmaxf(v, 0.f);
        Cbz[off] = f2bf(v);
      }
    }
  }
}

// ---------------- FF2 split-K=4 reduce (row-interleaved bf16 slices) ----------------
__global__ __launch_bounds__(256) void k_ff2_reduce(
    unsigned short* __restrict__ slices, const float* __restrict__ bias,
    const unsigned short* __restrict__ resid, float* __restrict__ partials) {
  __shared__ float red[8];
  int i = blockIdx.x;
  size_t rb = (size_t)i * 4096;
  int c = threadIdx.x * 4;
  u16x4 a0 = *(const u16x4*)(slices + rb + c);
  u16x4 a1 = *(const u16x4*)(slices + rb + 1024 + c);
  u16x4 a2 = *(const u16x4*)(slices + rb + 2048 + c);
  u16x4 a3 = *(const u16x4*)(slices + rb + 3072 + c);
  float4 bv = *(const float4*)(bias + c);
  u16x4 rv = *(const u16x4*)(resid + (size_t)i * 1024 + c);
  float4 o;
  o.x = bf2f(a0.x) + bf2f(a1.x) + bf2f(a2.x) + bf2f(a3.x) + bv.x + bf2f(rv.x);
  o.y = bf2f(a0.y) + bf2f(a1.y) + bf2f(a2.y) + bf2f(a3.y) + bv.y + bf2f(rv.y);
  o.z = bf2f(a0.z) + bf2f(a1.z) + bf2f(a2.z) + bf2f(a3.z) + bv.z + bf2f(rv.z);
  o.w = bf2f(a0.w) + bf2f(a1.w) + bf2f(a2.w) + bf2f(a3.w) + bv.w + bf2f(rv.w);
  __syncthreads();
  *(float4*)((float*)slices + (size_t)i * 2048 + c) = o;
  float bsum = o.x + o.y + o.z + o.w;
  float bsq = o.x * o.x + o.y * o.y + o.z * o.z + o.w * o.w;
  int wv = threadIdx.x >> 6, lv = threadIdx.x & 63;
#pragma unroll
  for (int mk = 1; mk < 64; mk <<= 1) { bsum += __shfl_xor(bsum, mk); bsq += __shfl_xor(bsq, mk); }
  if (lv == 0) { red[wv] = bsum; red[4 + wv] = bsq; }
  __syncthreads();
  if (threadIdx.x == 0) {
    partials[i * 2] = red[0] + red[1] + red[2] + red[3];
    partials[i * 2 + 1] = red[4] + red[5] + red[6] + red[7];
  }
}

// ---------------- V transpose per head: (s, d) -> (d, s), bf16 ----------------
__global__ __launch_bounds__(256) void k_transpose_v(const unsigned short* __restrict__ V, int ldv,
                                                     unsigned short* __restrict__ Vt, int S, int H) {
  __shared__ __align__(16) unsigned short t[64][72];
  int s0 = blockIdx.x * 64;
  int bh = blockIdx.y; int b = bh / H, h = bh % H;
  const unsigned short* src = V + (size_t)(b * S) * ldv + h * 64;
  unsigned short* dst = Vt + (size_t)bh * 64 * S;
  int tid = threadIdx.x;
#pragma unroll
  for (int i = 0; i < 2; ++i) {
    int idx = tid + i * 256;
    int s = idx >> 3, c = (idx & 7) * 8;
    s16x8 v = *(const s16x8*)(src + (size_t)(s0 + s) * ldv + c);
#pragma unroll
    for (int j = 0; j < 8; ++j) t[c + j][s] = (unsigned short)v[j];
  }
  __syncthreads();
#pragma unroll
  for (int i = 0; i < 2; ++i) {
    int idx = tid + i * 256;
    int d = idx >> 3, c = (idx & 7) * 8;
    *(s16x8*)(dst + (size_t)d * S + s0 + c) = *(const s16x8*)&t[d][c];
  }
}

// ---------------- causal flash attention + residual + LN partials ----------------
// log2-domain softmax (Q pre-scaled by 0.125*log2e -> bare v_exp_f32), native
// bf16 casts (v_cvt_pk), LDS exactly 40960 B -> 4 blocks/CU, bf16 output.
__global__ __launch_bounds__(256) void k_attn(
    const unsigned short* __restrict__ Qg, const unsigned short* __restrict__ Kg,
    const unsigned short* __restrict__ Vt, int ldqk,
    const float* __restrict__ x, unsigned short* __restrict__ hpre,
    float* __restrict__ partials, int S, int H) {
  __shared__ __align__(16) unsigned short Ks[2][64 * 64];
  __shared__ __align__(16) unsigned short Vs[2][64 * 64];
  __shared__ __align__(16) unsigned short Ps[4][16 * 64];
  int bh = blockIdx.x, b = bh >> 4, h = bh & 15;
  const int nqt = S / 64;
  int qt = nqt - 1 - (int)blockIdx.y;   // heavy tiles dispatched first
  int tid = threadIdx.x, w = tid >> 6, l = tid & 63;
  const int U = H * 64;
  const unsigned short* Qb = Qg + (size_t)(b * S) * ldqk + h * 64;
  const unsigned short* Kb = Kg + (size_t)(b * S) * ldqk + h * 64;
  const unsigned short* Vb = Vt + (size_t)bh * 64 * S;
  const float* xb = x + (size_t)(b * S) * U + h * 64;
  unsigned short* hb = hpre + (size_t)(b * S) * U + h * 64;
  int sg_r[2], sg_c[2];
#pragma unroll
  for (int it = 0; it < 2; ++it) {
    int g = it * 256 + tid;
    sg_r[it] = g >> 3;
    sg_c[it] = ((g & 7) ^ ((g >> 3) & 7)) * 8;
  }
  unsigned short* Pw = &Ps[w][0];
  int qloc = l & 15;
  int kloc = (l >> 4) * 4;

  int qrow = qt * 64 + w * 16 + qloc;
  s16x8 qf0 = *(const s16x8*)(Qb + (size_t)qrow * ldqk + (l >> 4) * 8);
  s16x8 qf1 = *(const s16x8*)(Qb + (size_t)qrow * ldqk + 32 + (l >> 4) * 8);
  f32x4 o[4] = {};
  float m = -1e30f, lsum = 0.f;

#pragma unroll
  for (int it = 0; it < 2; ++it) {
    GLDS16(Kb + (size_t)sg_r[it] * ldqk + sg_c[it], &Ks[0][(it * 256 + tid) * 8]);
    GLDS16(Vb + (size_t)sg_r[it] * S + sg_c[it], &Vs[0][(it * 256 + tid) * 8]);
  }

  for (int kt = 0; kt <= qt; ++kt) {
    int cur = kt & 1;
    __syncthreads();
    if (kt < qt) {
      int nb = cur ^ 1, kn = (kt + 1) * 64;
#pragma unroll
      for (int it = 0; it < 2; ++it) {
        GLDS16(Kb + (size_t)(kn + sg_r[it]) * ldqk + sg_c[it], &Ks[nb][(it * 256 + tid) * 8]);
        GLDS16(Vb + (size_t)sg_r[it] * S + kn + sg_c[it], &Vs[nb][(it * 256 + tid) * 8]);
      }
    }
    // ---- QK^T swapped: sc[fn][j] = S[key = fn*16+kloc+j][q = qloc] (log2 domain) ----
    f32x4 sc[4];
    __builtin_amdgcn_s_setprio(1);
#pragma unroll
    for (int fn = 0; fn < 4; ++fn) {
      int row = fn * 16 + (l & 15);
      s16x8 kf0 = *(const s16x8*)&Ks[cur][row * 64 + ((((l >> 4)) ^ (row & 7)) * 8)];
      s16x8 kf1 = *(const s16x8*)&Ks[cur][row * 64 + (((4 + (l >> 4)) ^ (row & 7)) * 8)];
      f32x4 z = {};
      z = MFMA(kf0, qf0, z);
      z = MFMA(kf1, qf1, z);
      sc[fn] = z;
    }
    __builtin_amdgcn_s_setprio(0);
    if (kt == qt) {
      int qsel = w * 16 + qloc;
#pragma unroll
      for (int fn = 0; fn < 4; ++fn)
#pragma unroll
        for (int j = 0; j < 4; ++j)
          if (fn * 16 + kloc + j > qsel) sc[fn][j] = -1e30f;
    }
    float mx = sc[0][0];
#pragma unroll
    for (int fn = 0; fn < 4; ++fn)
#pragma unroll
      for (int j = 0; j < 4; ++j) mx = fmaxf(mx, sc[fn][j]);
    mx = fmaxf(mx, __shfl_xor(mx, 16));
    mx = fmaxf(mx, __shfl_xor(mx, 32));
    // defer-max: threshold 8*log2e in log2 domain
    if (__ballot(mx > m + 11.5415603f)) {
      float mnew = fmaxf(m, mx);
      float alpha = exp2f(m - mnew);
      m = mnew;
      lsum *= alpha;
#pragma unroll
      for (int j = 0; j < 4; ++j) {
        float aj = __shfl(alpha, (l & 48) | (kloc + j));
#pragma unroll
        for (int fd = 0; fd < 4; ++fd) o[fd][j] *= aj;
      }
    }
    float rs = 0.f;
#pragma unroll
    for (int fn = 0; fn < 4; ++fn) {
      u16x4 pk;
#pragma unroll
      for (int j = 0; j < 4; ++j) {
        float p = exp2f(sc[fn][j] - m);
        rs += p;
        ((unsigned short*)&pk)[j] = f2bf(p);
      }
      int kb2 = fn * 16 + kloc;
      int el = qloc * 64 + (((kb2 >> 3) ^ (qloc & 7)) * 8) + (kb2 & 7);
      *(u16x4*)&Pw[el] = pk;
    }
    rs += __shfl_xor(rs, 16);
    rs += __shfl_xor(rs, 32);
    lsum += rs;
    __builtin_amdgcn_s_setprio(1);
#pragma unroll
    for (int kk = 0; kk < 2; ++kk) {
      int prow = l & 15;
      s16x8 pa = *(const s16x8*)&Pw[prow * 64 + (((kk * 4 + (l >> 4)) ^ (prow & 7)) * 8)];
#pragma unroll
      for (int fd = 0; fd < 4; ++fd) {
        int vrow = fd * 16 + (l & 15);
        s16x8 vf = *(const s16x8*)&Vs[cur][vrow * 64 + (((kk * 4 + (l >> 4)) ^ (vrow & 7)) * 8)];
        o[fd] = MFMA(pa, vf, o[fd]);
      }
    }
    __builtin_amdgcn_s_setprio(0);
  }
  // ---- epilogue: O/l + x residual -> bf16, LN partials via own Ps region ----
  float bsum = 0.f, bsq = 0.f;
#pragma unroll
  for (int j = 0; j < 4; ++j) {
    float lr = __shfl(lsum, (l & 48) | (kloc + j));
    float inv = 1.f / lr;
    int row = qt * 64 + w * 16 + kloc + j;
#pragma unroll
    for (int fd = 0; fd < 4; ++fd) {
      int col = fd * 16 + (l & 15);
      float v = o[fd][j] * inv + xb[(size_t)row * U + col];
      hb[(size_t)row * U + col] = f2bf(v);
      bsum += v; bsq += v * v;
    }
  }
#pragma unroll
  for (int mk = 1; mk < 64; mk <<= 1) { bsum += __shfl_xor(bsum, mk); bsq += __shfl_xor(bsq, mk); }
  if (l == 0) { float* r = (float*)&Ps[w][0]; r[0] = bsum; r[1] = bsq; }  // own region, post-loop
  __syncthreads();
  if (tid == 0) {
    float s2 = 0.f, q2 = 0.f;
#pragma unroll
    for (int ww = 0; ww < 4; ++ww) { const float* r = (const float*)&Ps[ww][0]; s2 += r[0]; q2 += r[1]; }
    int pi = b * (H * nqt) + h * nqt + qt;
    partials[pi * 2] = s2; partials[pi * 2 + 1] = q2;
  }
}

// ---------------- LN over (S,U) per batch ----------------
__global__ __launch_bounds__(256) void k_ln_stats(const float* __restrict__ partials, int nper,
                                                  float* __restrict__ stats, float invN) {
  int b = blockIdx.x, tid = threadIdx.x;
  float s = 0.f, q = 0.f;
  for (int i = tid; i < nper; i += 256) { s += partials[(b * nper + i) * 2]; q += partials[(b * nper + i) * 2 + 1]; }
#pragma unroll
  for (int mk = 1; mk < 64; mk <<= 1) { s += __shfl_xor(s, mk); q += __shfl_xor(q, mk); }
  __shared__ float red[8];
  int w = tid >> 6, l = tid & 63;
  if (l == 0) { red[w] = s; red[4 + w] = q; }
  __syncthreads();
  if (tid == 0) {
    s = red[0] + red[1] + red[2] + red[3];
    q = red[4] + red[5] + red[6] + red[7];
    float m = s * invN, var = q * invN - m * m;
    stats[b * 2] = m; stats[b * 2 + 1] = rsqrtf(var + 1e-5f);
  }
}

// LN apply from bf16 src -> bf16 out (LN1 path)
__global__ __launch_bounds__(256) void k_ln_apply_b(
    const unsigned short* __restrict__ src, const float* __restrict__ stats,
    const float* __restrict__ g, const float* __restrict__ bt,
    unsigned short* __restrict__ outb, int SU) {
  int b = blockIdx.y;
  int idx = (blockIdx.x * 256 + threadIdx.x) * 4;
  float m = stats[b * 2], r = stats[b * 2 + 1];
  u16x4 v4 = *(const u16x4*)(src + (size_t)b * SU + idx);
  float4 gg = *(const float4*)(g + idx);
  float4 bb = *(const float4*)(bt + idx);
  u16x4 ob;
  ob.x = f2bf((bf2f(v4.x) - m) * r * gg.x + bb.x);
  ob.y = f2bf((bf2f(v4.y) - m) * r * gg.y + bb.y);
  ob.z = f2bf((bf2f(v4.z) - m) * r * gg.z + bb.z);
  ob.w = f2bf((bf2f(v4.w) - m) * r * gg.w + bb.w);
  *(u16x4*)(outb + (size_t)b * SU + idx) = ob;
}

// LN apply from stride-2048 f32 rows (FF2 reduce output) -> d_out
__global__ __launch_bounds__(256) void k_ln_apply2(
    const float* __restrict__ src, const float* __restrict__ stats,
    const float* __restrict__ g, const float* __restrict__ bt,
    float* __restrict__ outf) {
  int b = blockIdx.y;
  int row = blockIdx.x;
  int grow = b * 2048 + row;
  int c = threadIdx.x * 4;
  float m = stats[b * 2], r = stats[b * 2 + 1];
  float4 v = *(const float4*)(src + (size_t)grow * 2048 + c);
  float4 gg = *(const float4*)(g + (size_t)row * 1024 + c);
  float4 bb = *(const float4*)(bt + (size_t)row * 1024 + c);
  float4 o;
  o.x = (v.x - m) * r * gg.x + bb.x;
  o.y = (v.y - m) * r * gg.y + bb.y;
  o.z = (v.z - m) * r * gg.z + bb.z;
  o.w = (v.w - m) * r * gg.w + bb.w;
  *(float4*)(outf + (size_t)grow * 1024 + c) = o;
}

extern "C" void kernel_launch(void* const* d_in, const int* in_sizes, int n_in,
                              void* d_out, int out_size, void* d_ws, size_t ws_size,
                              hipStream_t stream) {
  (void)in_sizes; (void)n_in; (void)out_size; (void)ws_size;
  const int S = 2048, H = 16;
  const float* x   = (const float*)d_in[0];
  const float* wq  = (const float*)d_in[1];
  const float* bq  = (const float*)d_in[2];
  const float* wk  = (const float*)d_in[3];
  const float* bk  = (const float*)d_in[4];
  const float* wv  = (const float*)d_in[5];
  const float* bv  = (const float*)d_in[6];
  const float* wf1 = (const float*)d_in[7];
  const float* bf1 = (const float*)d_in[8];
  const float* wf2 = (const float*)d_in[9];
  const float* bf2 = (const float*)d_in[10];
  const float* lng = (const float*)d_in[11];
  const float* lnb = (const float*)d_in[12];
  const float* ffg = (const float*)d_in[13];
  const float* ffb = (const float*)d_in[14];

  char* ws = (char*)d_ws;
  unsigned short* wqkvT = (unsigned short*)(ws);              // 3072x1024 bf16 (dead after QKV)
  unsigned short* wf1T  = (unsigned short*)(ws + 6291456);    // 4096x1024 bf16 (dead after FF1)
  unsigned short* wf2T  = (unsigned short*)(ws + 14680064);   // 1024x4096 bf16
  unsigned short* xb    = (unsigned short*)(ws + 23068672);   // 4096x1024 bf16 (dead after QKV)
  unsigned short* qkv   = (unsigned short*)(ws + 31457280);   // 4096x3072 bf16 (dead after attn)
  unsigned short* vt    = (unsigned short*)(ws + 56623104);   // 32x64x2048 bf16 (dead after attn)
  unsigned short* h1b   = (unsigned short*)(ws + 65011712);   // 4096x1024 bf16 (LN1 out)
  unsigned short* hpreb = (unsigned short*)(ws + 73400320);   // 4096x1024 bf16 (attn out, dead after LN1)
  unsigned short* ff2s  = (unsigned short*)(ws + 73400320);   // FF2 slices: 4096x4096 bf16 (over hpreb)
  unsigned short* f1b   = (unsigned short*)(ws + 23068672);   // 4096x4096 bf16 (over xb+qkv)
  float* biasqkv        = (float*)(ws + 106954752);           // 3072 f32
  float* part_attn      = (float*)(ws + 106967040);           // 2*512*2 f32
  float* stats1         = (float*)(ws + 106977280);           // 2*2 f32
  float* ffpart2        = (float*)(ws);                       // 4096*2 f32 (over wqkvT, dead)
  float* stats2         = (float*)(ws + 65536);               // 2*2 f32 (over wqkvT, dead)

  // Q path pre-scaled by 0.125 * log2(e) for log2-domain softmax
  const float qscale = 0.125f * 1.44269504f;
  k_f32_to_bf16<<<4096, 256, 0, stream>>>(x, xb, 4096 * 1024 / 4);
  k_transpose_w<<<dim3(16, 16), 256, 0, stream>>>(wq, wqkvT, 1024, 1024, qscale);
  k_transpose_w<<<dim3(16, 16), 256, 0, stream>>>(wk, wqkvT + 1024 * 1024, 1024, 1024, 1.0f);
  k_transpose_w<<<dim3(16, 16), 256, 0, stream>>>(wv, wqkvT + 2048 * 1024, 1024, 1024, 1.0f);
  k_transpose_w<<<dim3(16, 64), 256, 0, stream>>>(wf1, wf1T, 1024, 4096, 1.0f);
  k_transpose_w<<<dim3(64, 16), 256, 0, stream>>>(wf2, wf2T, 4096, 1024, 1.0f);
  k_concat3<<<12, 256, 0, stream>>>(bq, bk, bv, biasqkv, 1024, qscale);

  // QKV projection: (4096x1024) @ (1024x3072)
  k_gemm8<0><<<dim3(192, 1, 1), 512, 0, stream>>>(xb, 1024, wqkvT, 1024, biasqkv,
      qkv, nullptr, 3072, 1024, 12, 0);

  k_transpose_v<<<dim3(32, 32), 256, 0, stream>>>(qkv + 2048, 3072, vt, S, H);

  // causal flash attention + x residual -> bf16 + LN1 partials
  k_attn<<<dim3(32, 32), 256, 0, stream>>>(qkv, qkv + 1024, vt, 3072, x, hpreb, part_attn, S, H);

  // LN1 -> bf16
  k_ln_stats<<<2, 256, 0, stream>>>(part_attn, 512, stats1, 1.f / (2048.f * 1024.f));
  k_ln_apply_b<<<dim3(2048, 2), 256, 0, stream>>>(hpreb, stats1, lng, lnb, h1b, S * 1024);

  // FF1: (4096x1024) @ (1024x4096), ReLU
  k_gemm8<1><<<dim3(256, 1, 1), 512, 0, stream>>>(h1b, 1024, wf1T, 1024, bf1,
      f1b, nullptr, 4096, 1024, 16, 0);

  // FF2: (4096x4096) @ (4096x1024), split-K=4, bf16 row-interleaved slices
  k_gemm8<3><<<dim3(64, 1, 4), 512, 0, stream>>>(f1b, 4096, wf2T, 4096, nullptr,
      ff2s, nullptr, 4096, 1024, 4, 1024);

  // reduce slices + bias + bf16 residual -> f32 rows (stride 2048), LN2 partials
  k_ff2_reduce<<<4096, 256, 0, stream>>>(ff2s, bf2, h1b, ffpart2);

  // LN2 -> d_out (fp32)
  k_ln_stats<<<2, 256, 0, stream>>>(ffpart2, 2048, stats2, 1.f / (2048.f * 1024.f));
  k_ln_apply2<<<dim3(2048, 2), 256, 0, stream>>>((float*)ff2s, stats2, ffg, ffb, (float*)d_out);
}